// Round 2
// baseline (1201.945 us; speedup 1.0000x reference)
//
#include <hip/hip_runtime.h>

// ---------------------------------------------------------------------------
// EnhancedBitcoinGCN: 3x GCNConv + LN/residual + (trivial) MHA + MLP head
// N=100000 nodes, E=600000 edges, dims 164->128->128->64->32->16->32->1
// ALL float tensors are float32 (per reference jnp.float32). edge_index int32.
// ws layout: dinv[n] f32, agg[n*128] f32, A[n*128] f32, B[n*128] f32 (~154MB)
// Buffer ping-pong: A=h -> B=xw1 -> B=h1 -> A=xw2 -> B=h2 -> A=xw3
// ---------------------------------------------------------------------------

// ---------------- degree ----------------
__global__ void k_deg_init(float* __restrict__ deg, int n) {
  int i = blockIdx.x * blockDim.x + threadIdx.x;
  if (i < n) deg[i] = 1.0f;
}

__global__ void k_deg_count(const int* __restrict__ dst, float* __restrict__ deg, int e) {
  int i = blockIdx.x * blockDim.x + threadIdx.x;
  if (i < e) atomicAdd(&deg[dst[i]], 1.0f);
}

__global__ void k_dinv(float* __restrict__ deg, int n) {
  int i = blockIdx.x * blockDim.x + threadIdx.x;
  if (i < n) deg[i] = rsqrtf(deg[i]);
}

// ---------------- input layer: h = LN(relu(x@Wi+bi)) ----------------
// block = 128 threads (one per output col), NPB=8 nodes per block.
__global__ __launch_bounds__(128) void k_input(
    const float* __restrict__ x, const float* __restrict__ Wi,
    const float* __restrict__ bi, const float* __restrict__ g1,
    const float* __restrict__ b1, float* __restrict__ h, int n) {
  const int IN_D = 164, OUT_D = 128, NPB = 8;
  __shared__ float xs[NPB * IN_D];  // 1312 f32 = 328 float4
  __shared__ float red[2][NPB][2];
  int base = blockIdx.x * NPB;
  int tid = threadIdx.x;
  if (base + NPB <= n) {  // fast path: full block, float4 staging
    const float4* src4 = reinterpret_cast<const float4*>(x + (size_t)base * IN_D);
    float4* xs4 = reinterpret_cast<float4*>(xs);
    for (int i = tid; i < NPB * IN_D / 4; i += 128) xs4[i] = src4[i];
  } else {
    for (int i = tid; i < NPB * IN_D; i += 128) {
      size_t g = (size_t)base * IN_D + i;
      xs[i] = (g < (size_t)n * IN_D) ? x[g] : 0.0f;
    }
  }
  __syncthreads();
  int c = tid;
  float acc[NPB];
#pragma unroll
  for (int j = 0; j < NPB; j++) acc[j] = 0.0f;
  for (int k = 0; k < IN_D; k++) {
    float w = Wi[k * OUT_D + c];  // coalesced across threads
#pragma unroll
    for (int j = 0; j < NPB; j++) acc[j] += xs[j * IN_D + k] * w;  // LDS broadcast
  }
  float bb = bi[c], gv = g1[c], bv_ = b1[c];
  float v[NPB], s1[NPB], s2[NPB];
#pragma unroll
  for (int j = 0; j < NPB; j++) {
    float t = acc[j] + bb;
    t = t > 0.0f ? t : 0.0f;
    v[j] = t; s1[j] = t; s2[j] = t * t;
  }
#pragma unroll
  for (int off = 1; off < 64; off <<= 1) {
#pragma unroll
    for (int j = 0; j < NPB; j++) {
      s1[j] += __shfl_xor(s1[j], off);
      s2[j] += __shfl_xor(s2[j], off);
    }
  }
  int wave = tid >> 6;
  if ((tid & 63) == 0) {
#pragma unroll
    for (int j = 0; j < NPB; j++) { red[wave][j][0] = s1[j]; red[wave][j][1] = s2[j]; }
  }
  __syncthreads();
#pragma unroll
  for (int j = 0; j < NPB; j++) {
    if (base + j < n) {
      float S1 = red[0][j][0] + red[1][j][0];
      float S2 = red[0][j][1] + red[1][j][1];
      float m = S1 * (1.0f / 128.0f);
      float var = S2 * (1.0f / 128.0f) - m * m;
      float rs = rsqrtf(var + 1e-5f);
      h[(size_t)(base + j) * OUT_D + c] = (v[j] - m) * rs * gv + bv_;
    }
  }
}

// ---------------- per-conv node GEMM: xw = in@W ; agg = xw*dinv^2 + bias ----
template <int IN_D, int OUT_D>
__global__ __launch_bounds__(128) void k_xw(
    const float* __restrict__ in, const float* __restrict__ W,
    const float* __restrict__ bias, const float* __restrict__ dinv,
    float* __restrict__ xw, float* __restrict__ agg, int n) {
  constexpr int NPB = 8;
  constexpr int GROUPS = 128 / OUT_D;
  constexpr int NPT = NPB / GROUPS;  // nodes handled per thread
  __shared__ float xs[NPB * IN_D];
  int base = blockIdx.x * NPB;
  int tid = threadIdx.x;
  if (base + NPB <= n) {
    const float4* src4 = reinterpret_cast<const float4*>(in + (size_t)base * IN_D);
    float4* xs4 = reinterpret_cast<float4*>(xs);
    for (int i = tid; i < NPB * IN_D / 4; i += 128) xs4[i] = src4[i];
  } else {
    for (int i = tid; i < NPB * IN_D; i += 128) {
      size_t g = (size_t)base * IN_D + i;
      xs[i] = (g < (size_t)n * IN_D) ? in[g] : 0.0f;
    }
  }
  __syncthreads();
  int col = tid % OUT_D;
  int grp = tid / OUT_D;
  float acc[NPT];
#pragma unroll
  for (int j = 0; j < NPT; j++) acc[j] = 0.0f;
  for (int k = 0; k < IN_D; k++) {
    float w = W[k * OUT_D + col];
#pragma unroll
    for (int j = 0; j < NPT; j++) acc[j] += xs[(grp * NPT + j) * IN_D + k] * w;
  }
  float bc = bias[col];
#pragma unroll
  for (int j = 0; j < NPT; j++) {
    int node = base + grp * NPT + j;
    if (node < n) {
      float di = dinv[node];
      xw[(size_t)node * OUT_D + col] = acc[j];
      agg[(size_t)node * OUT_D + col] = acc[j] * di * di + bc;  // self-loop + bias
    }
  }
}

// ---------------- edge scatter: agg[dst] += xw[src]*dinv[src]*dinv[dst] -----
template <int OUT_D>
__global__ __launch_bounds__(256) void k_edge(
    const int* __restrict__ src, const int* __restrict__ dst,
    const float* __restrict__ xw, const float* __restrict__ dinv,
    float* __restrict__ agg, int e) {
  constexpr int LPE = OUT_D / 2;   // lanes per edge (2 cols per lane, float2)
  constexpr int EPW = 64 / LPE;    // edges per wave
  int gtid = blockIdx.x * blockDim.x + threadIdx.x;
  int gw = gtid >> 6;
  int lane = gtid & 63;
  int sub = lane / LPE;
  int li = lane % LPE;
  int eidx = gw * EPW + sub;
  if (eidx >= e) return;
  int s = src[eidx], d = dst[eidx];
  float norm = dinv[s] * dinv[d];
  float2 val = reinterpret_cast<const float2*>(xw + (size_t)s * OUT_D)[li];
  float* a = agg + (size_t)d * OUT_D + 2 * li;
  atomicAdd(a, val.x * norm);
  atomicAdd(a + 1, val.y * norm);
}

// ---------------- conv1 finalize: h1 = relu(agg) + h (float4) --------------
__global__ void k_fin1(const float4* __restrict__ agg, const float4* __restrict__ h,
                       float4* __restrict__ h1, size_t total4) {
  size_t i = (size_t)blockIdx.x * blockDim.x + threadIdx.x;
  if (i < total4) {
    float4 a = agg[i];
    float4 r = h[i];
    r.x += a.x > 0.0f ? a.x : 0.0f;
    r.y += a.y > 0.0f ? a.y : 0.0f;
    r.z += a.z > 0.0f ? a.z : 0.0f;
    r.w += a.w > 0.0f ? a.w : 0.0f;
    h1[i] = r;
  }
}

// ---------------- conv2 finalize: h2 = LN(relu(agg)) over 64 cols ----------
__global__ __launch_bounds__(256) void k_fin2(
    const float* __restrict__ agg, const float* __restrict__ g2,
    const float* __restrict__ b2, float* __restrict__ h2, int n) {
  int gtid = blockIdx.x * blockDim.x + threadIdx.x;
  int node = gtid >> 6;  // one wave (64 lanes) per node
  int lane = gtid & 63;
  if (node >= n) return;
  float v = agg[(size_t)node * 64 + lane];
  v = v > 0.0f ? v : 0.0f;
  float s1 = v, s2 = v * v;
#pragma unroll
  for (int off = 1; off < 64; off <<= 1) {
    s1 += __shfl_xor(s1, off);
    s2 += __shfl_xor(s2, off);
  }
  float m = s1 * (1.0f / 64.0f);
  float var = s2 * (1.0f / 64.0f) - m * m;
  float rs = rsqrtf(var + 1e-5f);
  h2[(size_t)node * 64 + lane] = (v - m) * rs * g2[lane] + b2[lane];
}

// ---------------- tail: relu(agg3) -> Wv -> Wo -> Wc1 -> Wc2 -> Wc3 --------
// (MHA with seq_len==1: softmax over one key == 1, so out = (x@Wv+bv)@Wo+bo)
__global__ __launch_bounds__(256) void k_tail(
    const float* __restrict__ agg3, const float* __restrict__ Wv,
    const float* __restrict__ bv, const float* __restrict__ Wo,
    const float* __restrict__ bo, const float* __restrict__ Wc1,
    const float* __restrict__ bc1, const float* __restrict__ Wc2,
    const float* __restrict__ bc2, const float* __restrict__ Wc3,
    const float* __restrict__ bc3, float* __restrict__ out, int n) {
  __shared__ float sWv[1024], sWo[1024], sWc1[512], sWc2[512];
  __shared__ float sbv[32], sbo[32], sbc2[32], sWc3[32], sbc1[16], sbc3[1];
  int tid = threadIdx.x;
  for (int i = tid; i < 1024; i += 256) { sWv[i] = Wv[i]; sWo[i] = Wo[i]; }
  for (int i = tid; i < 512; i += 256) { sWc1[i] = Wc1[i]; sWc2[i] = Wc2[i]; }
  if (tid < 32) { sbv[tid] = bv[tid]; sbo[tid] = bo[tid];
                  sbc2[tid] = bc2[tid]; sWc3[tid] = Wc3[tid]; }
  if (tid < 16) sbc1[tid] = bc1[tid];
  if (tid == 0) sbc3[0] = bc3[0];
  __syncthreads();
  int node = blockIdx.x * blockDim.x + tid;
  if (node >= n) return;
  float a[32];
  const float4* row4 = reinterpret_cast<const float4*>(agg3 + (size_t)node * 32);
#pragma unroll
  for (int q = 0; q < 8; q++) {
    float4 t = row4[q];
    a[4 * q + 0] = t.x > 0.0f ? t.x : 0.0f;
    a[4 * q + 1] = t.y > 0.0f ? t.y : 0.0f;
    a[4 * q + 2] = t.z > 0.0f ? t.z : 0.0f;
    a[4 * q + 3] = t.w > 0.0f ? t.w : 0.0f;
  }
  float v[32];
#pragma unroll
  for (int j = 0; j < 32; j++) v[j] = sbv[j];
  for (int k = 0; k < 32; k++) {
#pragma unroll
    for (int j = 0; j < 32; j++) v[j] += a[k] * sWv[k * 32 + j];
  }
  float o[32];
#pragma unroll
  for (int j = 0; j < 32; j++) o[j] = sbo[j];
  for (int k = 0; k < 32; k++) {
#pragma unroll
    for (int j = 0; j < 32; j++) o[j] += v[k] * sWo[k * 32 + j];
  }
  float c1[16];
#pragma unroll
  for (int j = 0; j < 16; j++) c1[j] = sbc1[j];
  for (int k = 0; k < 32; k++) {
#pragma unroll
    for (int j = 0; j < 16; j++) c1[j] += o[k] * sWc1[k * 16 + j];
  }
#pragma unroll
  for (int j = 0; j < 16; j++) c1[j] = c1[j] > 0.0f ? c1[j] : 0.0f;
  float c2[32];
#pragma unroll
  for (int j = 0; j < 32; j++) c2[j] = sbc2[j];
  for (int k = 0; k < 16; k++) {
#pragma unroll
    for (int j = 0; j < 32; j++) c2[j] += c1[k] * sWc2[k * 32 + j];
  }
  float r = sbc3[0];
#pragma unroll
  for (int k = 0; k < 32; k++) {
    float c = c2[k] > 0.0f ? c2[k] : 0.0f;
    r += c * sWc3[k];
  }
  out[node] = r;
}

// ---------------------------------------------------------------------------
extern "C" void kernel_launch(void* const* d_in, const int* in_sizes, int n_in,
                              void* d_out, int out_size, void* d_ws, size_t ws_size,
                              hipStream_t stream) {
  const float* x   = (const float*)d_in[0];
  const int* ei    = (const int*)d_in[1];
  const float* Wi  = (const float*)d_in[2];
  const float* bi  = (const float*)d_in[3];
  const float* g1  = (const float*)d_in[4];
  const float* b1  = (const float*)d_in[5];
  const float* Wg1 = (const float*)d_in[6];
  const float* bg1 = (const float*)d_in[7];
  const float* Wg2 = (const float*)d_in[8];
  const float* bg2 = (const float*)d_in[9];
  const float* g2  = (const float*)d_in[10];
  const float* b2  = (const float*)d_in[11];
  const float* Wg3 = (const float*)d_in[12];
  const float* bg3 = (const float*)d_in[13];
  // d_in[14..17]: Wq,bq,Wk,bk — mathematically dead (softmax over 1 key == 1)
  const float* Wv  = (const float*)d_in[18];
  const float* bv  = (const float*)d_in[19];
  const float* Wo  = (const float*)d_in[20];
  const float* bo  = (const float*)d_in[21];
  const float* Wc1 = (const float*)d_in[22];
  const float* bc1 = (const float*)d_in[23];
  const float* Wc2 = (const float*)d_in[24];
  const float* bc2 = (const float*)d_in[25];
  const float* Wc3 = (const float*)d_in[26];
  const float* bc3 = (const float*)d_in[27];

  const int n = in_sizes[0] / 164;
  const int e = in_sizes[1] / 2;
  const int* src = ei;
  const int* dst = ei + e;

  // workspace layout (256B aligned): dinv + agg + A + B  (~154 MB)
  char* ws = (char*)d_ws;
  size_t off = 0;
  auto alloc = [&](size_t bytes) {
    char* p = ws + off;
    off += (bytes + 255) & ~(size_t)255;
    return p;
  };
  float* dinv = (float*)alloc((size_t)n * 4);
  float* agg  = (float*)alloc((size_t)n * 128 * 4);
  float* A    = (float*)alloc((size_t)n * 128 * 4);
  float* B    = (float*)alloc((size_t)n * 128 * 4);
  (void)ws_size;

  const int BS = 256;
  // degree / dinv
  k_deg_init<<<(n + BS - 1) / BS, BS, 0, stream>>>(dinv, n);
  k_deg_count<<<(e + BS - 1) / BS, BS, 0, stream>>>(dst, dinv, e);
  k_dinv<<<(n + BS - 1) / BS, BS, 0, stream>>>(dinv, n);

  // input layer -> A = h [n,128]
  k_input<<<(n + 7) / 8, 128, 0, stream>>>(x, Wi, bi, g1, b1, A, n);

  auto edge_blocks = [&](int epw) {
    long long waves = ((long long)e + epw - 1) / epw;
    return (int)((waves * 64 + BS - 1) / BS);
  };

  // conv1: xw1 -> B, agg init; scatter; h1 = relu(agg)+h -> B (xw1 dead)
  k_xw<128, 128><<<(n + 7) / 8, 128, 0, stream>>>(A, Wg1, bg1, dinv, B, agg, n);
  k_edge<128><<<edge_blocks(1), BS, 0, stream>>>(src, dst, B, dinv, agg, e);
  {
    size_t total4 = (size_t)n * 128 / 4;
    k_fin1<<<(int)((total4 + BS - 1) / BS), BS, 0, stream>>>(
        (const float4*)agg, (const float4*)A, (float4*)B, total4);
  }

  // conv2: xw2 -> A [n,64] (h dead), agg init; scatter; h2 = LN(relu(agg)) -> B
  k_xw<128, 64><<<(n + 7) / 8, 128, 0, stream>>>(B, Wg2, bg2, dinv, A, agg, n);
  k_edge<64><<<edge_blocks(2), BS, 0, stream>>>(src, dst, A, dinv, agg, e);
  k_fin2<<<(int)(((size_t)n * 64 + BS - 1) / BS), BS, 0, stream>>>(agg, g2, b2, B, n);

  // conv3: xw3 -> A [n,32], agg init; scatter; tail reads agg directly
  k_xw<64, 32><<<(n + 7) / 8, 128, 0, stream>>>(B, Wg3, bg3, dinv, A, agg, n);
  k_edge<32><<<edge_blocks(4), BS, 0, stream>>>(src, dst, A, dinv, agg, e);

  // tail: relu(agg3) -> MHA(v,o) -> MLP -> out
  k_tail<<<(n + BS - 1) / BS, BS, 0, stream>>>(
      agg, Wv, bv, Wo, bo, Wc1, bc1, Wc2, bc2, Wc3, bc3, (float*)d_out, n);
}

// Round 3
// 514.973 us; speedup vs baseline: 2.3340x; 2.3340x over previous
//
#include <hip/hip_runtime.h>

// ---------------------------------------------------------------------------
// EnhancedBitcoinGCN: 3x GCNConv + LN/residual + (trivial) MHA + MLP head
// N=100000 nodes, E=600000 edges, dims 164->128->128->64->32->16->32->1
// Round 2 -> 3 change: replace f32-atomic edge scatter (586MB HBM write-through
// per conv, atomic-bound, 494us) with per-call CSR build + dst-side gather
// kernels that accumulate in registers (zero f32 atomics) and fuse the
// relu/residual/LN epilogues.
// ws: A,B,C [n*128] f32 ping-pong + dinv/counts/offsets/bsums + csr (~160MB)
// ---------------------------------------------------------------------------

__global__ void k_zero_int(int* __restrict__ p, int n) {
  int i = blockIdx.x * blockDim.x + threadIdx.x;
  if (i < n) p[i] = 0;
}

__global__ void k_count(const int* __restrict__ dst, int* __restrict__ counts, int e) {
  int i = blockIdx.x * blockDim.x + threadIdx.x;
  if (i < e) atomicAdd(&counts[dst[i]], 1);
}

// per-block (1024 elems) sums for exclusive scan
__global__ __launch_bounds__(256) void k_scan_part(
    const int* __restrict__ counts, int* __restrict__ bsums, int n) {
  int tid = threadIdx.x;
  int i0 = blockIdx.x * 1024 + tid * 4;
  int s = 0;
#pragma unroll
  for (int k = 0; k < 4; k++) { int i = i0 + k; if (i < n) s += counts[i]; }
#pragma unroll
  for (int d = 1; d < 64; d <<= 1) s += __shfl_xor(s, d);
  __shared__ int wsum[4];
  int lane = tid & 63, w = tid >> 6;
  if (lane == 0) wsum[w] = s;
  __syncthreads();
  if (tid == 0) bsums[blockIdx.x] = wsum[0] + wsum[1] + wsum[2] + wsum[3];
}

// exclusive scan of block sums (nb <= 128), single block of 128 threads
__global__ __launch_bounds__(128) void k_scan_top(int* __restrict__ bsums, int nb) {
  int tid = threadIdx.x;
  int orig = (tid < nb) ? bsums[tid] : 0;
  int v = orig;
  int lane = tid & 63, w = tid >> 6;
#pragma unroll
  for (int d = 1; d < 64; d <<= 1) { int t = __shfl_up(v, d); if (lane >= d) v += t; }
  __shared__ int ws[2];
  if (lane == 63) ws[w] = v;
  __syncthreads();
  if (w == 1) v += ws[0];
  if (tid < nb) bsums[tid] = v - orig;  // exclusive
}

// write final offsets + dinv = rsqrt(deg+1)
__global__ __launch_bounds__(256) void k_scan_down(
    const int* __restrict__ counts, const int* __restrict__ bsums,
    int* __restrict__ offsets, float* __restrict__ dinv, int n, int e) {
  int tid = threadIdx.x;
  int i0 = blockIdx.x * 1024 + tid * 4;
  int c[4]; int tsum = 0;
#pragma unroll
  for (int k = 0; k < 4; k++) { int i = i0 + k; c[k] = (i < n) ? counts[i] : 0; tsum += c[k]; }
  int v = tsum;
  int lane = tid & 63, w = tid >> 6;
#pragma unroll
  for (int d = 1; d < 64; d <<= 1) { int t = __shfl_up(v, d); if (lane >= d) v += t; }
  __shared__ int wsum[4];
  if (lane == 63) wsum[w] = v;
  __syncthreads();
  int wadd = 0;
#pragma unroll
  for (int q = 0; q < 4; q++) if (q < w) wadd += wsum[q];
  int run = (v - tsum) + wadd + bsums[blockIdx.x];
#pragma unroll
  for (int k = 0; k < 4; k++) {
    int i = i0 + k;
    if (i < n) { offsets[i] = run; dinv[i] = rsqrtf((float)(c[k] + 1)); }
    run += c[k];
  }
  if (blockIdx.x == 0 && tid == 0) offsets[n] = e;
}

// scatter edge ids into CSR buckets; precompute edge norm
__global__ void k_fill(const int* __restrict__ src, const int* __restrict__ dst,
                       const int* __restrict__ offsets, int* __restrict__ cursor,
                       const float* __restrict__ dinv, int* __restrict__ csr_src,
                       float* __restrict__ csr_norm, int e) {
  int i = blockIdx.x * blockDim.x + threadIdx.x;
  if (i >= e) return;
  int s = src[i], d = dst[i];
  int pos = atomicAdd(&cursor[d], 1);
  int idx = offsets[d] + pos;
  csr_src[idx] = s;
  csr_norm[idx] = dinv[s] * dinv[d];
}

// ---------------- input layer: h = LN(relu(x@Wi+bi)) ----------------
__global__ __launch_bounds__(128) void k_input(
    const float* __restrict__ x, const float* __restrict__ Wi,
    const float* __restrict__ bi, const float* __restrict__ g1,
    const float* __restrict__ b1, float* __restrict__ h, int n) {
  const int IN_D = 164, OUT_D = 128, NPB = 8;
  __shared__ float xs[NPB * IN_D];
  __shared__ float red[2][NPB][2];
  int base = blockIdx.x * NPB;
  int tid = threadIdx.x;
  if (base + NPB <= n) {
    const float4* src4 = reinterpret_cast<const float4*>(x + (size_t)base * IN_D);
    float4* xs4 = reinterpret_cast<float4*>(xs);
    for (int i = tid; i < NPB * IN_D / 4; i += 128) xs4[i] = src4[i];
  } else {
    for (int i = tid; i < NPB * IN_D; i += 128) {
      size_t g = (size_t)base * IN_D + i;
      xs[i] = (g < (size_t)n * IN_D) ? x[g] : 0.0f;
    }
  }
  __syncthreads();
  int c = tid;
  float acc[NPB];
#pragma unroll
  for (int j = 0; j < NPB; j++) acc[j] = 0.0f;
  for (int k = 0; k < IN_D; k++) {
    float w = Wi[k * OUT_D + c];
#pragma unroll
    for (int j = 0; j < NPB; j++) acc[j] += xs[j * IN_D + k] * w;
  }
  float bb = bi[c], gv = g1[c], bv_ = b1[c];
  float v[NPB], s1[NPB], s2[NPB];
#pragma unroll
  for (int j = 0; j < NPB; j++) {
    float t = acc[j] + bb;
    t = t > 0.0f ? t : 0.0f;
    v[j] = t; s1[j] = t; s2[j] = t * t;
  }
#pragma unroll
  for (int off = 1; off < 64; off <<= 1) {
#pragma unroll
    for (int j = 0; j < NPB; j++) {
      s1[j] += __shfl_xor(s1[j], off);
      s2[j] += __shfl_xor(s2[j], off);
    }
  }
  int wave = tid >> 6;
  if ((tid & 63) == 0) {
#pragma unroll
    for (int j = 0; j < NPB; j++) { red[wave][j][0] = s1[j]; red[wave][j][1] = s2[j]; }
  }
  __syncthreads();
#pragma unroll
  for (int j = 0; j < NPB; j++) {
    if (base + j < n) {
      float S1 = red[0][j][0] + red[1][j][0];
      float S2 = red[0][j][1] + red[1][j][1];
      float m = S1 * (1.0f / 128.0f);
      float var = S2 * (1.0f / 128.0f) - m * m;
      float rs = rsqrtf(var + 1e-5f);
      h[(size_t)(base + j) * OUT_D + c] = (v[j] - m) * rs * gv + bv_;
    }
  }
}

// ---------------- per-conv node GEMM: xw = in@W (pure) ----------------
template <int IN_D, int OUT_D>
__global__ __launch_bounds__(128) void k_xw(
    const float* __restrict__ in, const float* __restrict__ W,
    float* __restrict__ xw, int n) {
  constexpr int NPB = 8;
  constexpr int GROUPS = 128 / OUT_D;
  constexpr int NPT = NPB / GROUPS;
  __shared__ float xs[NPB * IN_D];
  int base = blockIdx.x * NPB;
  int tid = threadIdx.x;
  if (base + NPB <= n) {
    const float4* src4 = reinterpret_cast<const float4*>(in + (size_t)base * IN_D);
    float4* xs4 = reinterpret_cast<float4*>(xs);
    for (int i = tid; i < NPB * IN_D / 4; i += 128) xs4[i] = src4[i];
  } else {
    for (int i = tid; i < NPB * IN_D; i += 128) {
      size_t g = (size_t)base * IN_D + i;
      xs[i] = (g < (size_t)n * IN_D) ? in[g] : 0.0f;
    }
  }
  __syncthreads();
  int col = tid % OUT_D;
  int grp = tid / OUT_D;
  float acc[NPT];
#pragma unroll
  for (int j = 0; j < NPT; j++) acc[j] = 0.0f;
  for (int k = 0; k < IN_D; k++) {
    float w = W[k * OUT_D + col];
#pragma unroll
    for (int j = 0; j < NPT; j++) acc[j] += xs[(grp * NPT + j) * IN_D + k] * w;
  }
#pragma unroll
  for (int j = 0; j < NPT; j++) {
    int node = base + grp * NPT + j;
    if (node < n) xw[(size_t)node * OUT_D + col] = acc[j];
  }
}

// ---------------- dst-side gather + fused epilogue ----------------
// MODE 0: out = relu(agg) + aux1[node]   (conv1, residual)
// MODE 1: out = LN(relu(agg); g=aux1, b=aux2)  (conv2, OUT_D==64)
// MODE 2: out = agg                      (conv3, tail applies relu)
template <int OUT_D, int MODE>
__global__ __launch_bounds__(256) void k_gather(
    const int* __restrict__ off, const int* __restrict__ csr_src,
    const float* __restrict__ csr_norm, const float* __restrict__ xw,
    const float* __restrict__ dinv, const float* __restrict__ bias,
    const float* __restrict__ aux1, const float* __restrict__ aux2,
    float* __restrict__ out, int n) {
  constexpr int NPB = 256 / OUT_D;      // nodes per block
  constexpr int W = (OUT_D < 64) ? OUT_D : 64;  // shfl partition width
  int tid = threadIdx.x;
  int node = blockIdx.x * NPB + tid / OUT_D;
  int col = tid % OUT_D;
  if (node >= n) return;
  int start = off[node], end = off[node + 1];
  float di = dinv[node];
  float acc = xw[(size_t)node * OUT_D + col] * di * di + bias[col];  // self-loop
  int sl = tid % W;
  for (int base = start; base < end; base += W) {
    int m = end - base; m = m < W ? m : W;
    int sv = 0; float nv = 0.0f;
    if (sl < m) { sv = csr_src[base + sl]; nv = csr_norm[base + sl]; }
    for (int j = 0; j < m; j++) {
      int s = __shfl(sv, j, W);
      float nr = __shfl(nv, j, W);
      acc += xw[(size_t)s * OUT_D + col] * nr;  // coalesced 256B wave-read
    }
  }
  if (MODE == 0) {
    float v = acc > 0.0f ? acc : 0.0f;
    out[(size_t)node * OUT_D + col] = v + aux1[(size_t)node * OUT_D + col];
  } else if (MODE == 1) {
    float v = acc > 0.0f ? acc : 0.0f;
    float s1 = v, s2 = v * v;
#pragma unroll
    for (int d2 = 1; d2 < 64; d2 <<= 1) { s1 += __shfl_xor(s1, d2); s2 += __shfl_xor(s2, d2); }
    float m_ = s1 * (1.0f / OUT_D);
    float var = s2 * (1.0f / OUT_D) - m_ * m_;
    float rs = rsqrtf(var + 1e-5f);
    out[(size_t)node * OUT_D + col] = (v - m_) * rs * aux1[col] + aux2[col];
  } else {
    out[(size_t)node * OUT_D + col] = acc;
  }
}

// ---------------- tail: relu(agg3) -> Wv -> Wo -> Wc1 -> Wc2 -> Wc3 --------
// (MHA with seq_len==1: softmax over one key == 1, so out = (x@Wv+bv)@Wo+bo)
__global__ __launch_bounds__(256) void k_tail(
    const float* __restrict__ agg3, const float* __restrict__ Wv,
    const float* __restrict__ bv, const float* __restrict__ Wo,
    const float* __restrict__ bo, const float* __restrict__ Wc1,
    const float* __restrict__ bc1, const float* __restrict__ Wc2,
    const float* __restrict__ bc2, const float* __restrict__ Wc3,
    const float* __restrict__ bc3, float* __restrict__ out, int n) {
  __shared__ float sWv[1024], sWo[1024], sWc1[512], sWc2[512];
  __shared__ float sbv[32], sbo[32], sbc2[32], sWc3[32], sbc1[16], sbc3[1];
  int tid = threadIdx.x;
  for (int i = tid; i < 1024; i += 256) { sWv[i] = Wv[i]; sWo[i] = Wo[i]; }
  for (int i = tid; i < 512; i += 256) { sWc1[i] = Wc1[i]; sWc2[i] = Wc2[i]; }
  if (tid < 32) { sbv[tid] = bv[tid]; sbo[tid] = bo[tid];
                  sbc2[tid] = bc2[tid]; sWc3[tid] = Wc3[tid]; }
  if (tid < 16) sbc1[tid] = bc1[tid];
  if (tid == 0) sbc3[0] = bc3[0];
  __syncthreads();
  int node = blockIdx.x * blockDim.x + tid;
  if (node >= n) return;
  float a[32];
  const float4* row4 = reinterpret_cast<const float4*>(agg3 + (size_t)node * 32);
#pragma unroll
  for (int q = 0; q < 8; q++) {
    float4 t = row4[q];
    a[4 * q + 0] = t.x > 0.0f ? t.x : 0.0f;
    a[4 * q + 1] = t.y > 0.0f ? t.y : 0.0f;
    a[4 * q + 2] = t.z > 0.0f ? t.z : 0.0f;
    a[4 * q + 3] = t.w > 0.0f ? t.w : 0.0f;
  }
  float v[32];
#pragma unroll
  for (int j = 0; j < 32; j++) v[j] = sbv[j];
  for (int k = 0; k < 32; k++) {
#pragma unroll
    for (int j = 0; j < 32; j++) v[j] += a[k] * sWv[k * 32 + j];
  }
  float o[32];
#pragma unroll
  for (int j = 0; j < 32; j++) o[j] = sbo[j];
  for (int k = 0; k < 32; k++) {
#pragma unroll
    for (int j = 0; j < 32; j++) o[j] += v[k] * sWo[k * 32 + j];
  }
  float c1[16];
#pragma unroll
  for (int j = 0; j < 16; j++) c1[j] = sbc1[j];
  for (int k = 0; k < 32; k++) {
#pragma unroll
    for (int j = 0; j < 16; j++) c1[j] += o[k] * sWc1[k * 16 + j];
  }
#pragma unroll
  for (int j = 0; j < 16; j++) c1[j] = c1[j] > 0.0f ? c1[j] : 0.0f;
  float c2[32];
#pragma unroll
  for (int j = 0; j < 32; j++) c2[j] = sbc2[j];
  for (int k = 0; k < 16; k++) {
#pragma unroll
    for (int j = 0; j < 32; j++) c2[j] += c1[k] * sWc2[k * 32 + j];
  }
  float r = sbc3[0];
#pragma unroll
  for (int k = 0; k < 32; k++) {
    float c = c2[k] > 0.0f ? c2[k] : 0.0f;
    r += c * sWc3[k];
  }
  out[node] = r;
}

// ---------------------------------------------------------------------------
extern "C" void kernel_launch(void* const* d_in, const int* in_sizes, int n_in,
                              void* d_out, int out_size, void* d_ws, size_t ws_size,
                              hipStream_t stream) {
  const float* x   = (const float*)d_in[0];
  const int* ei    = (const int*)d_in[1];
  const float* Wi  = (const float*)d_in[2];
  const float* bi  = (const float*)d_in[3];
  const float* g1  = (const float*)d_in[4];
  const float* b1  = (const float*)d_in[5];
  const float* Wg1 = (const float*)d_in[6];
  const float* bg1 = (const float*)d_in[7];
  const float* Wg2 = (const float*)d_in[8];
  const float* bg2 = (const float*)d_in[9];
  const float* g2  = (const float*)d_in[10];
  const float* b2  = (const float*)d_in[11];
  const float* Wg3 = (const float*)d_in[12];
  const float* bg3 = (const float*)d_in[13];
  // d_in[14..17]: Wq,bq,Wk,bk — mathematically dead (softmax over 1 key == 1)
  const float* Wv  = (const float*)d_in[18];
  const float* bv  = (const float*)d_in[19];
  const float* Wo  = (const float*)d_in[20];
  const float* bo  = (const float*)d_in[21];
  const float* Wc1 = (const float*)d_in[22];
  const float* bc1 = (const float*)d_in[23];
  const float* Wc2 = (const float*)d_in[24];
  const float* bc2 = (const float*)d_in[25];
  const float* Wc3 = (const float*)d_in[26];
  const float* bc3 = (const float*)d_in[27];

  const int n = in_sizes[0] / 164;
  const int e = in_sizes[1] / 2;
  const int* src = ei;
  const int* dst = ei + e;

  // workspace layout (256B aligned)
  char* ws = (char*)d_ws;
  size_t off = 0;
  auto alloc = [&](size_t bytes) {
    char* p = ws + off;
    off += (bytes + 255) & ~(size_t)255;
    return p;
  };
  float* A        = (float*)alloc((size_t)n * 128 * 4);
  float* B        = (float*)alloc((size_t)n * 128 * 4);
  float* C        = (float*)alloc((size_t)n * 128 * 4);
  float* dinv     = (float*)alloc((size_t)n * 4);
  int*   counts   = (int*)alloc((size_t)n * 4);      // also reused as fill cursor
  int*   offsets  = (int*)alloc((size_t)(n + 1) * 4);
  int*   bsums    = (int*)alloc(128 * 4);
  int*   csr_src  = (int*)alloc((size_t)e * 4);
  float* csr_norm = (float*)alloc((size_t)e * 4);
  (void)ws_size;

  const int BS = 256;
  const int SB = (n + 1023) / 1024;  // scan blocks (98 for n=100k, <=128)

  // ---- CSR build (shared by all three convs) ----
  k_zero_int<<<(n + BS - 1) / BS, BS, 0, stream>>>(counts, n);
  k_count<<<(e + BS - 1) / BS, BS, 0, stream>>>(dst, counts, e);
  k_scan_part<<<SB, 256, 0, stream>>>(counts, bsums, n);
  k_scan_top<<<1, 128, 0, stream>>>(bsums, SB);
  k_scan_down<<<SB, 256, 0, stream>>>(counts, bsums, offsets, dinv, n, e);
  k_zero_int<<<(n + BS - 1) / BS, BS, 0, stream>>>(counts, n);  // cursor
  k_fill<<<(e + BS - 1) / BS, BS, 0, stream>>>(src, dst, offsets, counts, dinv,
                                               csr_src, csr_norm, e);

  // ---- input layer -> A = h [n,128] ----
  k_input<<<(n + 7) / 8, 128, 0, stream>>>(x, Wi, bi, g1, b1, A, n);

  // ---- conv1: xw1 = A@Wg1 -> B; gather -> C = h1 = relu(agg)+h ----
  k_xw<128, 128><<<(n + 7) / 8, 128, 0, stream>>>(A, Wg1, B, n);
  k_gather<128, 0><<<(n + 1) / 2, 256, 0, stream>>>(
      offsets, csr_src, csr_norm, B, dinv, bg1, A, nullptr, C, n);

  // ---- conv2: xw2 = C@Wg2 -> A [n,64]; gather -> B = h2 = LN(relu(agg)) ----
  k_xw<128, 64><<<(n + 7) / 8, 128, 0, stream>>>(C, Wg2, A, n);
  k_gather<64, 1><<<(n + 3) / 4, 256, 0, stream>>>(
      offsets, csr_src, csr_norm, A, dinv, bg2, g2, b2, B, n);

  // ---- conv3: xw3 = B@Wg3 -> A [n,32]; gather -> C = agg3 (raw) ----
  k_xw<64, 32><<<(n + 7) / 8, 128, 0, stream>>>(B, Wg3, A, n);
  k_gather<32, 2><<<(n + 7) / 8, 256, 0, stream>>>(
      offsets, csr_src, csr_norm, A, dinv, bg3, nullptr, nullptr, C, n);

  // ---- tail: relu(agg3) -> MHA(v,o) -> MLP -> out ----
  k_tail<<<(n + BS - 1) / BS, BS, 0, stream>>>(
      C, Wv, bv, Wo, bo, Wc1, bc1, Wc2, bc2, Wc3, bc3, (float*)d_out, n);
}

// Round 4
// 374.273 us; speedup vs baseline: 3.2114x; 1.3759x over previous
//
#include <hip/hip_runtime.h>

// ---------------------------------------------------------------------------
// EnhancedBitcoinGCN: 3x GCNConv + LN/residual + (trivial) MHA + MLP head
// N=100000 nodes, E=600000 edges, dims 164->128->128->64->32->16->32->1
// Round 3 -> 4 change: all four dense GEMMs (input 164->128 and the three
// conv GEMMs) move from VALU-bound fp32 loops (k_input 130us @ 69% VALUBusy)
// to MFMA bf16 with a 3-term hi/lo split (Ah*Bh + Ah*Bl + Al*Bh, f32 accum)
// -> ~f32 accuracy at matrix-core rates. CSR build + gathers + tail unchanged.
// ---------------------------------------------------------------------------

typedef __attribute__((ext_vector_type(8))) __bf16 bf16x8;
typedef __attribute__((ext_vector_type(4))) float f32x4;

static __device__ __forceinline__ void split_bf16(float v, __bf16& hi, __bf16& lo) {
  __bf16 h = (__bf16)v;       // RNE
  hi = h;
  lo = (__bf16)(v - (float)h);
}

// ---------------- CSR build ----------------
__global__ void k_zero_int(int* __restrict__ p, int n) {
  int i = blockIdx.x * blockDim.x + threadIdx.x;
  if (i < n) p[i] = 0;
}

__global__ void k_count(const int* __restrict__ dst, int* __restrict__ counts, int e) {
  int i = blockIdx.x * blockDim.x + threadIdx.x;
  if (i < e) atomicAdd(&counts[dst[i]], 1);
}

__global__ __launch_bounds__(256) void k_scan_part(
    const int* __restrict__ counts, int* __restrict__ bsums, int n) {
  int tid = threadIdx.x;
  int i0 = blockIdx.x * 1024 + tid * 4;
  int s = 0;
#pragma unroll
  for (int k = 0; k < 4; k++) { int i = i0 + k; if (i < n) s += counts[i]; }
#pragma unroll
  for (int d = 1; d < 64; d <<= 1) s += __shfl_xor(s, d);
  __shared__ int wsum[4];
  int lane = tid & 63, w = tid >> 6;
  if (lane == 0) wsum[w] = s;
  __syncthreads();
  if (tid == 0) bsums[blockIdx.x] = wsum[0] + wsum[1] + wsum[2] + wsum[3];
}

__global__ __launch_bounds__(128) void k_scan_top(int* __restrict__ bsums, int nb) {
  int tid = threadIdx.x;
  int orig = (tid < nb) ? bsums[tid] : 0;
  int v = orig;
  int lane = tid & 63, w = tid >> 6;
#pragma unroll
  for (int d = 1; d < 64; d <<= 1) { int t = __shfl_up(v, d); if (lane >= d) v += t; }
  __shared__ int ws[2];
  if (lane == 63) ws[w] = v;
  __syncthreads();
  if (w == 1) v += ws[0];
  if (tid < nb) bsums[tid] = v - orig;  // exclusive
}

__global__ __launch_bounds__(256) void k_scan_down(
    const int* __restrict__ counts, const int* __restrict__ bsums,
    int* __restrict__ offsets, float* __restrict__ dinv, int n, int e) {
  int tid = threadIdx.x;
  int i0 = blockIdx.x * 1024 + tid * 4;
  int c[4]; int tsum = 0;
#pragma unroll
  for (int k = 0; k < 4; k++) { int i = i0 + k; c[k] = (i < n) ? counts[i] : 0; tsum += c[k]; }
  int v = tsum;
  int lane = tid & 63, w = tid >> 6;
#pragma unroll
  for (int d = 1; d < 64; d <<= 1) { int t = __shfl_up(v, d); if (lane >= d) v += t; }
  __shared__ int wsum[4];
  if (lane == 63) wsum[w] = v;
  __syncthreads();
  int wadd = 0;
#pragma unroll
  for (int q = 0; q < 4; q++) if (q < w) wadd += wsum[q];
  int run = (v - tsum) + wadd + bsums[blockIdx.x];
#pragma unroll
  for (int k = 0; k < 4; k++) {
    int i = i0 + k;
    if (i < n) { offsets[i] = run; dinv[i] = rsqrtf((float)(c[k] + 1)); }
    run += c[k];
  }
  if (blockIdx.x == 0 && tid == 0) offsets[n] = e;
}

__global__ void k_fill(const int* __restrict__ src, const int* __restrict__ dst,
                       const int* __restrict__ offsets, int* __restrict__ cursor,
                       const float* __restrict__ dinv, int* __restrict__ csr_src,
                       float* __restrict__ csr_norm, int e) {
  int i = blockIdx.x * blockDim.x + threadIdx.x;
  if (i >= e) return;
  int s = src[i], d = dst[i];
  int pos = atomicAdd(&cursor[d], 1);
  int idx = offsets[d] + pos;
  csr_src[idx] = s;
  csr_norm[idx] = dinv[s] * dinv[d];
}

// ---------------- MFMA GEMM (bf16x3 split, f32 accuracy) ----------------
// out[M,N] = A[M,K] @ W[K,N]; block = 256 thr / 4 waves, 64 rows per block,
// wave w owns rows [w*16, w*16+16) x all N cols. K-step 32.
// Fragment layouts (mfma_f32_16x16x32_bf16):
//   A: lane l holds A[l&15][8*(l>>4)+i]  (16B contiguous -> ds_read_b128)
//   B: lane l holds B[8*(l>>4)+i][l&15]
//   D: col = lane&15, row = (lane>>4)*4 + reg   [guide-verified m89/m91]
// MODE 0: raw write. MODE 1: out = LN(relu(acc + bias); gamma, beta).
template <int K, int N, int MODE>
__global__ __launch_bounds__(256) void k_gemm(
    const float* __restrict__ A, const float* __restrict__ W,
    const float* __restrict__ bias, const float* __restrict__ gamma,
    const float* __restrict__ beta, float* __restrict__ out, int n) {
  constexpr int KS = (K + 31) / 32;
  constexpr int CT = N / 16;
  __shared__ __align__(16) __bf16 Ah[2048], Al[2048];        // 64 rows x 32 k
  __shared__ __align__(16) __bf16 Bh[CT * 512], Bl[CT * 512]; // 32 k x N
  int tid = threadIdx.x;
  int lane = tid & 63;
  int w = tid >> 6;
  int base = blockIdx.x * 64;
  f32x4 acc[CT];
#pragma unroll
  for (int c = 0; c < CT; c++) acc[c] = (f32x4)0.0f;

  for (int ks = 0; ks < KS; ks++) {
    // ---- stage A tile (fragment order, hi/lo split) ----
    {
      int row = base + w * 16 + (lane & 15);
      int gk = ks * 32 + (lane >> 4) * 8;
      float v[8];
      if (row < n && gk + 8 <= K) {
        const float4* p = reinterpret_cast<const float4*>(A + (size_t)row * K + gk);
        float4 u0 = p[0], u1 = p[1];
        v[0] = u0.x; v[1] = u0.y; v[2] = u0.z; v[3] = u0.w;
        v[4] = u1.x; v[5] = u1.y; v[6] = u1.z; v[7] = u1.w;
      } else {
#pragma unroll
        for (int i = 0; i < 8; i++)
          v[i] = (row < n && gk + i < K) ? A[(size_t)row * K + gk + i] : 0.0f;
      }
      int o = tid * 8;
#pragma unroll
      for (int i = 0; i < 8; i++) split_bf16(v[i], Ah[o + i], Al[o + i]);
    }
    // ---- stage B tile (fragment order, hi/lo split) ----
    for (int idx = tid; idx < CT * 64; idx += 256) {
      int bl = idx & 63;
      int ct = idx >> 6;
      int gcol = ct * 16 + (bl & 15);
      int gk0 = ks * 32 + (bl >> 4) * 8;
      int o = idx * 8;
#pragma unroll
      for (int i = 0; i < 8; i++) {
        float v = (gk0 + i < K) ? W[(size_t)(gk0 + i) * N + gcol] : 0.0f;
        split_bf16(v, Bh[o + i], Bl[o + i]);
      }
    }
    __syncthreads();
    bf16x8 ah = *reinterpret_cast<const bf16x8*>(&Ah[(size_t)tid * 8]);
    bf16x8 al = *reinterpret_cast<const bf16x8*>(&Al[(size_t)tid * 8]);
#pragma unroll
    for (int c = 0; c < CT; c++) {
      bf16x8 bh = *reinterpret_cast<const bf16x8*>(&Bh[(size_t)(c * 64 + lane) * 8]);
      bf16x8 bl2 = *reinterpret_cast<const bf16x8*>(&Bl[(size_t)(c * 64 + lane) * 8]);
      acc[c] = __builtin_amdgcn_mfma_f32_16x16x32_bf16(ah, bh, acc[c], 0, 0, 0);
      acc[c] = __builtin_amdgcn_mfma_f32_16x16x32_bf16(ah, bl2, acc[c], 0, 0, 0);
      acc[c] = __builtin_amdgcn_mfma_f32_16x16x32_bf16(al, bh, acc[c], 0, 0, 0);
    }
    __syncthreads();
  }

  int r0 = (lane >> 4) * 4;
  int li = lane & 15;
  if (MODE == 0) {
#pragma unroll
    for (int c = 0; c < CT; c++) {
#pragma unroll
      for (int r = 0; r < 4; r++) {
        int node = base + w * 16 + r0 + r;
        if (node < n) out[(size_t)node * N + c * 16 + li] = acc[c][r];
      }
    }
  } else {
    // bias + relu + LayerNorm over N cols (row lives in one 16-lane group)
    float s1[4] = {0, 0, 0, 0}, s2[4] = {0, 0, 0, 0};
#pragma unroll
    for (int c = 0; c < CT; c++) {
      float bb = bias[c * 16 + li];
#pragma unroll
      for (int r = 0; r < 4; r++) {
        float t = acc[c][r] + bb;
        t = t > 0.0f ? t : 0.0f;
        acc[c][r] = t;
        s1[r] += t;
        s2[r] += t * t;
      }
    }
#pragma unroll
    for (int m = 1; m < 16; m <<= 1) {
#pragma unroll
      for (int r = 0; r < 4; r++) {
        s1[r] += __shfl_xor(s1[r], m);
        s2[r] += __shfl_xor(s2[r], m);
      }
    }
#pragma unroll
    for (int c = 0; c < CT; c++) {
      float gv = gamma[c * 16 + li], bv = beta[c * 16 + li];
#pragma unroll
      for (int r = 0; r < 4; r++) {
        int node = base + w * 16 + r0 + r;
        if (node < n) {
          float mean = s1[r] * (1.0f / N);
          float var = s2[r] * (1.0f / N) - mean * mean;
          float rs = rsqrtf(var + 1e-5f);
          out[(size_t)node * N + c * 16 + li] = (acc[c][r] - mean) * rs * gv + bv;
        }
      }
    }
  }
}

// ---------------- dst-side gather + fused epilogue ----------------
// MODE 0: out = relu(agg) + aux1[node]   (conv1, residual)
// MODE 1: out = LN(relu(agg); g=aux1, b=aux2)  (conv2, OUT_D==64)
// MODE 2: out = agg                      (conv3, tail applies relu)
template <int OUT_D, int MODE>
__global__ __launch_bounds__(256) void k_gather(
    const int* __restrict__ off, const int* __restrict__ csr_src,
    const float* __restrict__ csr_norm, const float* __restrict__ xw,
    const float* __restrict__ dinv, const float* __restrict__ bias,
    const float* __restrict__ aux1, const float* __restrict__ aux2,
    float* __restrict__ out, int n) {
  constexpr int NPB = 256 / OUT_D;
  constexpr int W = (OUT_D < 64) ? OUT_D : 64;
  int tid = threadIdx.x;
  int node = blockIdx.x * NPB + tid / OUT_D;
  int col = tid % OUT_D;
  if (node >= n) return;
  int start = off[node], end = off[node + 1];
  float di = dinv[node];
  float acc = xw[(size_t)node * OUT_D + col] * di * di + bias[col];  // self-loop
  int sl = tid % W;
  for (int base = start; base < end; base += W) {
    int m = end - base; m = m < W ? m : W;
    int sv = 0; float nv = 0.0f;
    if (sl < m) { sv = csr_src[base + sl]; nv = csr_norm[base + sl]; }
    for (int j = 0; j < m; j++) {
      int s = __shfl(sv, j, W);
      float nr = __shfl(nv, j, W);
      acc += xw[(size_t)s * OUT_D + col] * nr;  // coalesced wave-read
    }
  }
  if (MODE == 0) {
    float v = acc > 0.0f ? acc : 0.0f;
    out[(size_t)node * OUT_D + col] = v + aux1[(size_t)node * OUT_D + col];
  } else if (MODE == 1) {
    float v = acc > 0.0f ? acc : 0.0f;
    float s1 = v, s2 = v * v;
#pragma unroll
    for (int d2 = 1; d2 < 64; d2 <<= 1) { s1 += __shfl_xor(s1, d2); s2 += __shfl_xor(s2, d2); }
    float m_ = s1 * (1.0f / OUT_D);
    float var = s2 * (1.0f / OUT_D) - m_ * m_;
    float rs = rsqrtf(var + 1e-5f);
    out[(size_t)node * OUT_D + col] = (v - m_) * rs * aux1[col] + aux2[col];
  } else {
    out[(size_t)node * OUT_D + col] = acc;
  }
}

// ---------------- tail: relu(agg3) -> Wv -> Wo -> Wc1 -> Wc2 -> Wc3 --------
// (MHA with seq_len==1: softmax over one key == 1, so out = (x@Wv+bv)@Wo+bo)
__global__ __launch_bounds__(256) void k_tail(
    const float* __restrict__ agg3, const float* __restrict__ Wv,
    const float* __restrict__ bv, const float* __restrict__ Wo,
    const float* __restrict__ bo, const float* __restrict__ Wc1,
    const float* __restrict__ bc1, const float* __restrict__ Wc2,
    const float* __restrict__ bc2, const float* __restrict__ Wc3,
    const float* __restrict__ bc3, float* __restrict__ out, int n) {
  __shared__ float sWv[1024], sWo[1024], sWc1[512], sWc2[512];
  __shared__ float sbv[32], sbo[32], sbc2[32], sWc3[32], sbc1[16], sbc3[1];
  int tid = threadIdx.x;
  for (int i = tid; i < 1024; i += 256) { sWv[i] = Wv[i]; sWo[i] = Wo[i]; }
  for (int i = tid; i < 512; i += 256) { sWc1[i] = Wc1[i]; sWc2[i] = Wc2[i]; }
  if (tid < 32) { sbv[tid] = bv[tid]; sbo[tid] = bo[tid];
                  sbc2[tid] = bc2[tid]; sWc3[tid] = Wc3[tid]; }
  if (tid < 16) sbc1[tid] = bc1[tid];
  if (tid == 0) sbc3[0] = bc3[0];
  __syncthreads();
  int node = blockIdx.x * blockDim.x + tid;
  if (node >= n) return;
  float a[32];
  const float4* row4 = reinterpret_cast<const float4*>(agg3 + (size_t)node * 32);
#pragma unroll
  for (int q = 0; q < 8; q++) {
    float4 t = row4[q];
    a[4 * q + 0] = t.x > 0.0f ? t.x : 0.0f;
    a[4 * q + 1] = t.y > 0.0f ? t.y : 0.0f;
    a[4 * q + 2] = t.z > 0.0f ? t.z : 0.0f;
    a[4 * q + 3] = t.w > 0.0f ? t.w : 0.0f;
  }
  float v[32];
#pragma unroll
  for (int j = 0; j < 32; j++) v[j] = sbv[j];
  for (int k = 0; k < 32; k++) {
#pragma unroll
    for (int j = 0; j < 32; j++) v[j] += a[k] * sWv[k * 32 + j];
  }
  float o[32];
#pragma unroll
  for (int j = 0; j < 32; j++) o[j] = sbo[j];
  for (int k = 0; k < 32; k++) {
#pragma unroll
    for (int j = 0; j < 32; j++) o[j] += v[k] * sWo[k * 32 + j];
  }
  float c1[16];
#pragma unroll
  for (int j = 0; j < 16; j++) c1[j] = sbc1[j];
  for (int k = 0; k < 32; k++) {
#pragma unroll
    for (int j = 0; j < 16; j++) c1[j] += o[k] * sWc1[k * 16 + j];
  }
#pragma unroll
  for (int j = 0; j < 16; j++) c1[j] = c1[j] > 0.0f ? c1[j] : 0.0f;
  float c2[32];
#pragma unroll
  for (int j = 0; j < 32; j++) c2[j] = sbc2[j];
  for (int k = 0; k < 16; k++) {
#pragma unroll
    for (int j = 0; j < 32; j++) c2[j] += c1[k] * sWc2[k * 32 + j];
  }
  float r = sbc3[0];
#pragma unroll
  for (int k = 0; k < 32; k++) {
    float c = c2[k] > 0.0f ? c2[k] : 0.0f;
    r += c * sWc3[k];
  }
  out[node] = r;
}

// ---------------------------------------------------------------------------
extern "C" void kernel_launch(void* const* d_in, const int* in_sizes, int n_in,
                              void* d_out, int out_size, void* d_ws, size_t ws_size,
                              hipStream_t stream) {
  const float* x   = (const float*)d_in[0];
  const int* ei    = (const int*)d_in[1];
  const float* Wi  = (const float*)d_in[2];
  const float* bi  = (const float*)d_in[3];
  const float* g1  = (const float*)d_in[4];
  const float* b1  = (const float*)d_in[5];
  const float* Wg1 = (const float*)d_in[6];
  const float* bg1 = (const float*)d_in[7];
  const float* Wg2 = (const float*)d_in[8];
  const float* bg2 = (const float*)d_in[9];
  const float* g2  = (const float*)d_in[10];
  const float* b2  = (const float*)d_in[11];
  const float* Wg3 = (const float*)d_in[12];
  const float* bg3 = (const float*)d_in[13];
  // d_in[14..17]: Wq,bq,Wk,bk — mathematically dead (softmax over 1 key == 1)
  const float* Wv  = (const float*)d_in[18];
  const float* bv  = (const float*)d_in[19];
  const float* Wo  = (const float*)d_in[20];
  const float* bo  = (const float*)d_in[21];
  const float* Wc1 = (const float*)d_in[22];
  const float* bc1 = (const float*)d_in[23];
  const float* Wc2 = (const float*)d_in[24];
  const float* bc2 = (const float*)d_in[25];
  const float* Wc3 = (const float*)d_in[26];
  const float* bc3 = (const float*)d_in[27];

  const int n = in_sizes[0] / 164;
  const int e = in_sizes[1] / 2;
  const int* src = ei;
  const int* dst = ei + e;

  // workspace layout (256B aligned)
  char* ws = (char*)d_ws;
  size_t off = 0;
  auto alloc = [&](size_t bytes) {
    char* p = ws + off;
    off += (bytes + 255) & ~(size_t)255;
    return p;
  };
  float* A        = (float*)alloc((size_t)n * 128 * 4);
  float* B        = (float*)alloc((size_t)n * 128 * 4);
  float* C        = (float*)alloc((size_t)n * 128 * 4);
  float* dinv     = (float*)alloc((size_t)n * 4);
  int*   counts   = (int*)alloc((size_t)n * 4);      // also reused as fill cursor
  int*   offsets  = (int*)alloc((size_t)(n + 1) * 4);
  int*   bsums    = (int*)alloc(128 * 4);
  int*   csr_src  = (int*)alloc((size_t)e * 4);
  float* csr_norm = (float*)alloc((size_t)e * 4);
  (void)ws_size;

  const int BS = 256;
  const int SB = (n + 1023) / 1024;  // scan blocks (98 for n=100k, <=128)
  const int GB = (n + 63) / 64;      // gemm blocks

  // ---- CSR build (shared by all three convs) ----
  k_zero_int<<<(n + BS - 1) / BS, BS, 0, stream>>>(counts, n);
  k_count<<<(e + BS - 1) / BS, BS, 0, stream>>>(dst, counts, e);
  k_scan_part<<<SB, 256, 0, stream>>>(counts, bsums, n);
  k_scan_top<<<1, 128, 0, stream>>>(bsums, SB);
  k_scan_down<<<SB, 256, 0, stream>>>(counts, bsums, offsets, dinv, n, e);
  k_zero_int<<<(n + BS - 1) / BS, BS, 0, stream>>>(counts, n);  // cursor
  k_fill<<<(e + BS - 1) / BS, BS, 0, stream>>>(src, dst, offsets, counts, dinv,
                                               csr_src, csr_norm, e);

  // ---- input layer: A = h = LN(relu(x@Wi+bi)) ----
  k_gemm<164, 128, 1><<<GB, 256, 0, stream>>>(x, Wi, bi, g1, b1, A, n);

  // ---- conv1: B = xw1 = h@Wg1; gather -> C = h1 = relu(agg)+h ----
  k_gemm<128, 128, 0><<<GB, 256, 0, stream>>>(A, Wg1, nullptr, nullptr, nullptr, B, n);
  k_gather<128, 0><<<(n + 1) / 2, 256, 0, stream>>>(
      offsets, csr_src, csr_norm, B, dinv, bg1, A, nullptr, C, n);

  // ---- conv2: A = xw2 = h1@Wg2 [n,64]; gather -> B = h2 = LN(relu(agg)) ----
  k_gemm<128, 64, 0><<<GB, 256, 0, stream>>>(C, Wg2, nullptr, nullptr, nullptr, A, n);
  k_gather<64, 1><<<(n + 3) / 4, 256, 0, stream>>>(
      offsets, csr_src, csr_norm, A, dinv, bg2, g2, b2, B, n);

  // ---- conv3: A = xw3 = h2@Wg3 [n,32]; gather -> C = agg3 (raw) ----
  k_gemm<64, 32, 0><<<GB, 256, 0, stream>>>(B, Wg3, nullptr, nullptr, nullptr, A, n);
  k_gather<32, 2><<<(n + 7) / 8, 256, 0, stream>>>(
      offsets, csr_src, csr_norm, A, dinv, bg3, nullptr, nullptr, C, n);

  // ---- tail: relu(agg3) -> MHA(v,o) -> MLP -> out ----
  k_tail<<<(n + BS - 1) / BS, BS, 0, stream>>>(
      C, Wv, bv, Wo, bo, Wc1, bc1, Wc2, bc2, Wc3, bc3, (float*)d_out, n);
}

// Round 5
// 288.130 us; speedup vs baseline: 4.1715x; 1.2990x over previous
//
#include <hip/hip_runtime.h>

// ---------------------------------------------------------------------------
// EnhancedBitcoinGCN: 3x GCNConv + LN/residual + (trivial) MHA + MLP head
// N=100000 nodes, E=600000 edges, dims 164->128->128->64->32->16->32->1
// Round 4 -> 5 change: gathers were the top dispatches (conv1 105us,
// FETCH 201MB, latency/traffic-bound). All intermediates (h, xw, h1, h2)
// now stored fp16 (halves gather/GEMM activation traffic; 2^-11 rel err),
// and the gather processes 2 cols/thread via f16x2 loads (one wave-read per
// edge row instead of two). GEMMs stay MFMA bf16-3-term; CSR + tail as-is.
// ---------------------------------------------------------------------------

typedef __attribute__((ext_vector_type(8))) __bf16 bf16x8;
typedef __attribute__((ext_vector_type(4))) float f32x4;
typedef __attribute__((ext_vector_type(2))) _Float16 f16x2;
typedef __attribute__((ext_vector_type(8))) _Float16 f16x8;

static __device__ __forceinline__ void split_bf16(float v, __bf16& hi, __bf16& lo) {
  __bf16 h = (__bf16)v;       // RNE
  hi = h;
  lo = (__bf16)(v - (float)h);
}

// ---------------- CSR build ----------------
__global__ void k_zero_int(int* __restrict__ p, int n) {
  int i = blockIdx.x * blockDim.x + threadIdx.x;
  if (i < n) p[i] = 0;
}

__global__ void k_count(const int* __restrict__ dst, int* __restrict__ counts, int e) {
  int i = blockIdx.x * blockDim.x + threadIdx.x;
  if (i < e) atomicAdd(&counts[dst[i]], 1);
}

__global__ __launch_bounds__(256) void k_scan_part(
    const int* __restrict__ counts, int* __restrict__ bsums, int n) {
  int tid = threadIdx.x;
  int i0 = blockIdx.x * 1024 + tid * 4;
  int s = 0;
#pragma unroll
  for (int k = 0; k < 4; k++) { int i = i0 + k; if (i < n) s += counts[i]; }
#pragma unroll
  for (int d = 1; d < 64; d <<= 1) s += __shfl_xor(s, d);
  __shared__ int wsum[4];
  int lane = tid & 63, w = tid >> 6;
  if (lane == 0) wsum[w] = s;
  __syncthreads();
  if (tid == 0) bsums[blockIdx.x] = wsum[0] + wsum[1] + wsum[2] + wsum[3];
}

__global__ __launch_bounds__(128) void k_scan_top(int* __restrict__ bsums, int nb) {
  int tid = threadIdx.x;
  int orig = (tid < nb) ? bsums[tid] : 0;
  int v = orig;
  int lane = tid & 63, w = tid >> 6;
#pragma unroll
  for (int d = 1; d < 64; d <<= 1) { int t = __shfl_up(v, d); if (lane >= d) v += t; }
  __shared__ int ws[2];
  if (lane == 63) ws[w] = v;
  __syncthreads();
  if (w == 1) v += ws[0];
  if (tid < nb) bsums[tid] = v - orig;  // exclusive
}

__global__ __launch_bounds__(256) void k_scan_down(
    const int* __restrict__ counts, const int* __restrict__ bsums,
    int* __restrict__ offsets, float* __restrict__ dinv, int n, int e) {
  int tid = threadIdx.x;
  int i0 = blockIdx.x * 1024 + tid * 4;
  int c[4]; int tsum = 0;
#pragma unroll
  for (int k = 0; k < 4; k++) { int i = i0 + k; c[k] = (i < n) ? counts[i] : 0; tsum += c[k]; }
  int v = tsum;
  int lane = tid & 63, w = tid >> 6;
#pragma unroll
  for (int d = 1; d < 64; d <<= 1) { int t = __shfl_up(v, d); if (lane >= d) v += t; }
  __shared__ int wsum[4];
  if (lane == 63) wsum[w] = v;
  __syncthreads();
  int wadd = 0;
#pragma unroll
  for (int q = 0; q < 4; q++) if (q < w) wadd += wsum[q];
  int run = (v - tsum) + wadd + bsums[blockIdx.x];
#pragma unroll
  for (int k = 0; k < 4; k++) {
    int i = i0 + k;
    if (i < n) { offsets[i] = run; dinv[i] = rsqrtf((float)(c[k] + 1)); }
    run += c[k];
  }
  if (blockIdx.x == 0 && tid == 0) offsets[n] = e;
}

__global__ void k_fill(const int* __restrict__ src, const int* __restrict__ dst,
                       const int* __restrict__ offsets, int* __restrict__ cursor,
                       const float* __restrict__ dinv, int* __restrict__ csr_src,
                       float* __restrict__ csr_norm, int e) {
  int i = blockIdx.x * blockDim.x + threadIdx.x;
  if (i >= e) return;
  int s = src[i], d = dst[i];
  int pos = atomicAdd(&cursor[d], 1);
  int idx = offsets[d] + pos;
  csr_src[idx] = s;
  csr_norm[idx] = dinv[s] * dinv[d];
}

// ---------------- MFMA GEMM (bf16x3 split, ~f32 accuracy) ----------------
// out[M,N] = A[M,K] @ W[K,N]; block = 256 thr / 4 waves, 64 rows per block.
// A fragment: lane l holds A[l&15][8*(l>>4)+i]; B: B[8*(l>>4)+i][l&15];
// D: col = lane&15, row = (lane>>4)*4 + reg.
// MODE 0: raw write. MODE 1: out = LN(relu(acc + bias); gamma, beta).
template <int K, int N, int MODE, typename InT, typename OutT>
__global__ __launch_bounds__(256) void k_gemm(
    const InT* __restrict__ A, const float* __restrict__ W,
    const float* __restrict__ bias, const float* __restrict__ gamma,
    const float* __restrict__ beta, OutT* __restrict__ out, int n) {
  constexpr int KS = (K + 31) / 32;
  constexpr int CT = N / 16;
  __shared__ __align__(16) __bf16 Ah[2048], Al[2048];         // 64 rows x 32 k
  __shared__ __align__(16) __bf16 Bh[CT * 512], Bl[CT * 512]; // 32 k x N
  int tid = threadIdx.x;
  int lane = tid & 63;
  int w = tid >> 6;
  int base = blockIdx.x * 64;
  f32x4 acc[CT];
#pragma unroll
  for (int c = 0; c < CT; c++) acc[c] = (f32x4)0.0f;

  for (int ks = 0; ks < KS; ks++) {
    // ---- stage A tile (fragment order, hi/lo split) ----
    {
      int row = base + w * 16 + (lane & 15);
      int gk = ks * 32 + (lane >> 4) * 8;
      float v[8];
      if (row < n && gk + 8 <= K) {
        if constexpr (sizeof(InT) == 4) {
          const float4* p = reinterpret_cast<const float4*>(
              reinterpret_cast<const float*>(A) + (size_t)row * K + gk);
          float4 u0 = p[0], u1 = p[1];
          v[0] = u0.x; v[1] = u0.y; v[2] = u0.z; v[3] = u0.w;
          v[4] = u1.x; v[5] = u1.y; v[6] = u1.z; v[7] = u1.w;
        } else {
          f16x8 hv = *reinterpret_cast<const f16x8*>(
              reinterpret_cast<const _Float16*>(A) + (size_t)row * K + gk);
#pragma unroll
          for (int i = 0; i < 8; i++) v[i] = (float)hv[i];
        }
      } else {
#pragma unroll
        for (int i = 0; i < 8; i++)
          v[i] = (row < n && gk + i < K) ? (float)A[(size_t)row * K + gk + i] : 0.0f;
      }
      int o = tid * 8;
#pragma unroll
      for (int i = 0; i < 8; i++) split_bf16(v[i], Ah[o + i], Al[o + i]);
    }
    // ---- stage B tile (weights f32, fragment order, hi/lo split) ----
    for (int idx = tid; idx < CT * 64; idx += 256) {
      int bl = idx & 63;
      int ct = idx >> 6;
      int gcol = ct * 16 + (bl & 15);
      int gk0 = ks * 32 + (bl >> 4) * 8;
      int o = idx * 8;
#pragma unroll
      for (int i = 0; i < 8; i++) {
        float v = (gk0 + i < K) ? W[(size_t)(gk0 + i) * N + gcol] : 0.0f;
        split_bf16(v, Bh[o + i], Bl[o + i]);
      }
    }
    __syncthreads();
    bf16x8 ah = *reinterpret_cast<const bf16x8*>(&Ah[(size_t)tid * 8]);
    bf16x8 al = *reinterpret_cast<const bf16x8*>(&Al[(size_t)tid * 8]);
#pragma unroll
    for (int c = 0; c < CT; c++) {
      bf16x8 bh = *reinterpret_cast<const bf16x8*>(&Bh[(size_t)(c * 64 + lane) * 8]);
      bf16x8 bl2 = *reinterpret_cast<const bf16x8*>(&Bl[(size_t)(c * 64 + lane) * 8]);
      acc[c] = __builtin_amdgcn_mfma_f32_16x16x32_bf16(ah, bh, acc[c], 0, 0, 0);
      acc[c] = __builtin_amdgcn_mfma_f32_16x16x32_bf16(ah, bl2, acc[c], 0, 0, 0);
      acc[c] = __builtin_amdgcn_mfma_f32_16x16x32_bf16(al, bh, acc[c], 0, 0, 0);
    }
    __syncthreads();
  }

  int r0 = (lane >> 4) * 4;
  int li = lane & 15;
  if (MODE == 0) {
#pragma unroll
    for (int c = 0; c < CT; c++) {
#pragma unroll
      for (int r = 0; r < 4; r++) {
        int node = base + w * 16 + r0 + r;
        if (node < n) out[(size_t)node * N + c * 16 + li] = (OutT)acc[c][r];
      }
    }
  } else {
    float s1[4] = {0, 0, 0, 0}, s2[4] = {0, 0, 0, 0};
#pragma unroll
    for (int c = 0; c < CT; c++) {
      float bb = bias[c * 16 + li];
#pragma unroll
      for (int r = 0; r < 4; r++) {
        float t = acc[c][r] + bb;
        t = t > 0.0f ? t : 0.0f;
        acc[c][r] = t;
        s1[r] += t;
        s2[r] += t * t;
      }
    }
#pragma unroll
    for (int m = 1; m < 16; m <<= 1) {
#pragma unroll
      for (int r = 0; r < 4; r++) {
        s1[r] += __shfl_xor(s1[r], m);
        s2[r] += __shfl_xor(s2[r], m);
      }
    }
#pragma unroll
    for (int c = 0; c < CT; c++) {
      float gv = gamma[c * 16 + li], bv = beta[c * 16 + li];
#pragma unroll
      for (int r = 0; r < 4; r++) {
        int node = base + w * 16 + r0 + r;
        if (node < n) {
          float mean = s1[r] * (1.0f / N);
          float var = s2[r] * (1.0f / N) - mean * mean;
          float rs = rsqrtf(var + 1e-5f);
          out[(size_t)node * N + c * 16 + li] = (OutT)((acc[c][r] - mean) * rs * gv + bv);
        }
      }
    }
  }
}

// ---------------- dst-side gather + fused epilogue (fp16 rows) -------------
// Each thread owns 2 cols (f16x2); TPN = OUT_D/2 lanes per node -> one
// wave-read per edge row. Edge meta broadcast via __shfl over the TPN group.
// MODE 0: out = relu(agg) + auxh[node]           (conv1, fp16 out)
// MODE 1: out = LN(relu(agg); gamma, beta)       (conv2, fp16 out)
// MODE 2: out = agg                              (conv3, f32 out for tail)
template <int OUT_D, int MODE, typename OutT>
__global__ __launch_bounds__(256) void k_gather(
    const int* __restrict__ off, const int* __restrict__ csr_src,
    const float* __restrict__ csr_norm, const _Float16* __restrict__ xw,
    const float* __restrict__ dinv, const float* __restrict__ bias,
    const _Float16* __restrict__ auxh, const float* __restrict__ gamma,
    const float* __restrict__ beta, OutT* __restrict__ out, int n) {
  constexpr int TPN = OUT_D / 2;   // threads per node (<=64: one wave group)
  constexpr int NPB = 256 / TPN;
  int tid = threadIdx.x;
  int node = blockIdx.x * NPB + tid / TPN;
  int li = tid % TPN;              // col-pair index; also lane-in-group
  if (node >= n) return;
  int start = off[node], end = off[node + 1];
  float di = dinv[node];
  f16x2 self = *reinterpret_cast<const f16x2*>(xw + (size_t)node * OUT_D + 2 * li);
  float a0 = (float)self[0] * di * di + bias[2 * li];
  float a1 = (float)self[1] * di * di + bias[2 * li + 1];
  for (int base = start; base < end; base += TPN) {
    int m = end - base; m = m < TPN ? m : TPN;
    int sv = 0; float nv = 0.0f;
    if (li < m) { sv = csr_src[base + li]; nv = csr_norm[base + li]; }
    for (int j = 0; j < m; j++) {
      int s = __shfl(sv, j, TPN);
      float nr = __shfl(nv, j, TPN);
      f16x2 val = *reinterpret_cast<const f16x2*>(xw + (size_t)s * OUT_D + 2 * li);
      a0 += (float)val[0] * nr;
      a1 += (float)val[1] * nr;
    }
  }
  if constexpr (MODE == 0) {
    f16x2 hres = *reinterpret_cast<const f16x2*>(auxh + (size_t)node * OUT_D + 2 * li);
    float v0 = (a0 > 0.0f ? a0 : 0.0f) + (float)hres[0];
    float v1 = (a1 > 0.0f ? a1 : 0.0f) + (float)hres[1];
    f16x2 o; o[0] = (_Float16)v0; o[1] = (_Float16)v1;
    *reinterpret_cast<f16x2*>(reinterpret_cast<_Float16*>(out) +
                              (size_t)node * OUT_D + 2 * li) = o;
  } else if constexpr (MODE == 1) {
    float v0 = a0 > 0.0f ? a0 : 0.0f;
    float v1 = a1 > 0.0f ? a1 : 0.0f;
    float s1 = v0 + v1, s2 = v0 * v0 + v1 * v1;
#pragma unroll
    for (int d2 = 1; d2 < TPN; d2 <<= 1) {
      s1 += __shfl_xor(s1, d2, TPN);
      s2 += __shfl_xor(s2, d2, TPN);
    }
    float m_ = s1 * (1.0f / OUT_D);
    float var = s2 * (1.0f / OUT_D) - m_ * m_;
    float rs = rsqrtf(var + 1e-5f);
    f16x2 o;
    o[0] = (_Float16)((v0 - m_) * rs * gamma[2 * li] + beta[2 * li]);
    o[1] = (_Float16)((v1 - m_) * rs * gamma[2 * li + 1] + beta[2 * li + 1]);
    *reinterpret_cast<f16x2*>(reinterpret_cast<_Float16*>(out) +
                              (size_t)node * OUT_D + 2 * li) = o;
  } else {
    float* po = reinterpret_cast<float*>(out) + (size_t)node * OUT_D + 2 * li;
    po[0] = a0;
    po[1] = a1;
  }
}

// ---------------- tail: relu(agg3) -> Wv -> Wo -> Wc1 -> Wc2 -> Wc3 --------
// (MHA with seq_len==1: softmax over one key == 1, so out = (x@Wv+bv)@Wo+bo)
__global__ __launch_bounds__(256) void k_tail(
    const float* __restrict__ agg3, const float* __restrict__ Wv,
    const float* __restrict__ bv, const float* __restrict__ Wo,
    const float* __restrict__ bo, const float* __restrict__ Wc1,
    const float* __restrict__ bc1, const float* __restrict__ Wc2,
    const float* __restrict__ bc2, const float* __restrict__ Wc3,
    const float* __restrict__ bc3, float* __restrict__ out, int n) {
  __shared__ float sWv[1024], sWo[1024], sWc1[512], sWc2[512];
  __shared__ float sbv[32], sbo[32], sbc2[32], sWc3[32], sbc1[16], sbc3[1];
  int tid = threadIdx.x;
  for (int i = tid; i < 1024; i += 256) { sWv[i] = Wv[i]; sWo[i] = Wo[i]; }
  for (int i = tid; i < 512; i += 256) { sWc1[i] = Wc1[i]; sWc2[i] = Wc2[i]; }
  if (tid < 32) { sbv[tid] = bv[tid]; sbo[tid] = bo[tid];
                  sbc2[tid] = bc2[tid]; sWc3[tid] = Wc3[tid]; }
  if (tid < 16) sbc1[tid] = bc1[tid];
  if (tid == 0) sbc3[0] = bc3[0];
  __syncthreads();
  int node = blockIdx.x * blockDim.x + tid;
  if (node >= n) return;
  float a[32];
  const float4* row4 = reinterpret_cast<const float4*>(agg3 + (size_t)node * 32);
#pragma unroll
  for (int q = 0; q < 8; q++) {
    float4 t = row4[q];
    a[4 * q + 0] = t.x > 0.0f ? t.x : 0.0f;
    a[4 * q + 1] = t.y > 0.0f ? t.y : 0.0f;
    a[4 * q + 2] = t.z > 0.0f ? t.z : 0.0f;
    a[4 * q + 3] = t.w > 0.0f ? t.w : 0.0f;
  }
  float v[32];
#pragma unroll
  for (int j = 0; j < 32; j++) v[j] = sbv[j];
  for (int k = 0; k < 32; k++) {
#pragma unroll
    for (int j = 0; j < 32; j++) v[j] += a[k] * sWv[k * 32 + j];
  }
  float o[32];
#pragma unroll
  for (int j = 0; j < 32; j++) o[j] = sbo[j];
  for (int k = 0; k < 32; k++) {
#pragma unroll
    for (int j = 0; j < 32; j++) o[j] += v[k] * sWo[k * 32 + j];
  }
  float c1[16];
#pragma unroll
  for (int j = 0; j < 16; j++) c1[j] = sbc1[j];
  for (int k = 0; k < 32; k++) {
#pragma unroll
    for (int j = 0; j < 16; j++) c1[j] += o[k] * sWc1[k * 16 + j];
  }
#pragma unroll
  for (int j = 0; j < 16; j++) c1[j] = c1[j] > 0.0f ? c1[j] : 0.0f;
  float c2[32];
#pragma unroll
  for (int j = 0; j < 32; j++) c2[j] = sbc2[j];
  for (int k = 0; k < 16; k++) {
#pragma unroll
    for (int j = 0; j < 32; j++) c2[j] += c1[k] * sWc2[k * 32 + j];
  }
  float r = sbc3[0];
#pragma unroll
  for (int k = 0; k < 32; k++) {
    float c = c2[k] > 0.0f ? c2[k] : 0.0f;
    r += c * sWc3[k];
  }
  out[node] = r;
}

// ---------------------------------------------------------------------------
extern "C" void kernel_launch(void* const* d_in, const int* in_sizes, int n_in,
                              void* d_out, int out_size, void* d_ws, size_t ws_size,
                              hipStream_t stream) {
  const float* x   = (const float*)d_in[0];
  const int* ei    = (const int*)d_in[1];
  const float* Wi  = (const float*)d_in[2];
  const float* bi  = (const float*)d_in[3];
  const float* g1  = (const float*)d_in[4];
  const float* b1  = (const float*)d_in[5];
  const float* Wg1 = (const float*)d_in[6];
  const float* bg1 = (const float*)d_in[7];
  const float* Wg2 = (const float*)d_in[8];
  const float* bg2 = (const float*)d_in[9];
  const float* g2  = (const float*)d_in[10];
  const float* b2  = (const float*)d_in[11];
  const float* Wg3 = (const float*)d_in[12];
  const float* bg3 = (const float*)d_in[13];
  // d_in[14..17]: Wq,bq,Wk,bk — mathematically dead (softmax over 1 key == 1)
  const float* Wv  = (const float*)d_in[18];
  const float* bv  = (const float*)d_in[19];
  const float* Wo  = (const float*)d_in[20];
  const float* bo  = (const float*)d_in[21];
  const float* Wc1 = (const float*)d_in[22];
  const float* bc1 = (const float*)d_in[23];
  const float* Wc2 = (const float*)d_in[24];
  const float* bc2 = (const float*)d_in[25];
  const float* Wc3 = (const float*)d_in[26];
  const float* bc3 = (const float*)d_in[27];

  const int n = in_sizes[0] / 164;
  const int e = in_sizes[1] / 2;
  const int* src = ei;
  const int* dst = ei + e;

  // workspace layout (256B aligned)
  char* ws = (char*)d_ws;
  size_t off = 0;
  auto alloc = [&](size_t bytes) {
    char* p = ws + off;
    off += (bytes + 255) & ~(size_t)255;
    return p;
  };
  char* A         = alloc((size_t)n * 128 * 4);
  char* B         = alloc((size_t)n * 128 * 4);
  char* C         = alloc((size_t)n * 128 * 4);
  float* dinv     = (float*)alloc((size_t)n * 4);
  int*   counts   = (int*)alloc((size_t)n * 4);      // also reused as fill cursor
  int*   offsets  = (int*)alloc((size_t)(n + 1) * 4);
  int*   bsums    = (int*)alloc(128 * 4);
  int*   csr_src  = (int*)alloc((size_t)e * 4);
  float* csr_norm = (float*)alloc((size_t)e * 4);
  (void)ws_size;

  const int BS = 256;
  const int SB = (n + 1023) / 1024;  // scan blocks (98 for n=100k, <=128)
  const int GB = (n + 63) / 64;      // gemm blocks

  // ---- CSR build (shared by all three convs) ----
  k_zero_int<<<(n + BS - 1) / BS, BS, 0, stream>>>(counts, n);
  k_count<<<(e + BS - 1) / BS, BS, 0, stream>>>(dst, counts, e);
  k_scan_part<<<SB, 256, 0, stream>>>(counts, bsums, n);
  k_scan_top<<<1, 128, 0, stream>>>(bsums, SB);
  k_scan_down<<<SB, 256, 0, stream>>>(counts, bsums, offsets, dinv, n, e);
  k_zero_int<<<(n + BS - 1) / BS, BS, 0, stream>>>(counts, n);  // cursor
  k_fill<<<(e + BS - 1) / BS, BS, 0, stream>>>(src, dst, offsets, counts, dinv,
                                               csr_src, csr_norm, e);

  // ---- input layer: A = h = LN(relu(x@Wi+bi))  [fp16] ----
  k_gemm<164, 128, 1, float, _Float16><<<GB, 256, 0, stream>>>(
      x, Wi, bi, g1, b1, (_Float16*)A, n);

  // ---- conv1: B = xw1 = h@Wg1 [fp16]; gather -> C = h1 = relu(agg)+h ----
  k_gemm<128, 128, 0, _Float16, _Float16><<<GB, 256, 0, stream>>>(
      (_Float16*)A, Wg1, nullptr, nullptr, nullptr, (_Float16*)B, n);
  k_gather<128, 0, _Float16><<<(n + 3) / 4, 256, 0, stream>>>(
      offsets, csr_src, csr_norm, (const _Float16*)B, dinv, bg1,
      (const _Float16*)A, nullptr, nullptr, (_Float16*)C, n);

  // ---- conv2: A = xw2 = h1@Wg2 [n,64 fp16]; gather -> B = h2 = LN(relu) ----
  k_gemm<128, 64, 0, _Float16, _Float16><<<GB, 256, 0, stream>>>(
      (_Float16*)C, Wg2, nullptr, nullptr, nullptr, (_Float16*)A, n);
  k_gather<64, 1, _Float16><<<(n + 7) / 8, 256, 0, stream>>>(
      offsets, csr_src, csr_norm, (const _Float16*)A, dinv, bg2,
      nullptr, g2, b2, (_Float16*)B, n);

  // ---- conv3: A = xw3 = h2@Wg3 [n,32 fp16]; gather -> C = agg3 (f32) ----
  k_gemm<64, 32, 0, _Float16, _Float16><<<GB, 256, 0, stream>>>(
      (_Float16*)B, Wg3, nullptr, nullptr, nullptr, (_Float16*)A, n);
  k_gather<32, 2, float><<<(n + 15) / 16, 256, 0, stream>>>(
      offsets, csr_src, csr_norm, (const _Float16*)A, dinv, bg3,
      nullptr, nullptr, nullptr, (float*)C, n);

  // ---- tail: relu(agg3) -> MHA(v,o) -> MLP -> out ----
  k_tail<<<(n + BS - 1) / BS, BS, 0, stream>>>(
      (const float*)C, Wv, bv, Wo, bo, Wc1, bc1, Wc2, bc2, Wc3, bc3,
      (float*)d_out, n);
}

// Round 6
// 234.897 us; speedup vs baseline: 5.1169x; 1.2266x over previous
//
#include <hip/hip_runtime.h>

// ---------------------------------------------------------------------------
// EnhancedBitcoinGCN: 3x GCNConv + LN/residual + (trivial) MHA + MLP head
// N=100000 nodes, E=600000 edges, dims 164->128->128->64->32->16->32->1
// Round 5 -> 6:
//  * gather: 4 cols/thread (f16x4 8B loads) + 4-way unrolled edge loop
//    (4 loads in flight), packed int2 edge meta -> attacks latency-bound
//    conv1 gather (59us @ 21% HBM, 28% VALU).
//  * GEMMs: weights pre-split ONCE to fragment-ordered fp16 hi/lo (k_prepack);
//    whole prepacked W copied to LDS once per block (single barrier); A is
//    exact fp16 -> register-direct fragments, no LDS, no per-K-step sync;
//    2 MFMAs/tile via mfma_f32_16x16x32_f16. Input GEMM: x hi/lo fp16 split
//    (exact to 2^-22) x hi-only Wi.
//  * agg3 stored fp16 (tail reads halve).
// ---------------------------------------------------------------------------

typedef __attribute__((ext_vector_type(8))) _Float16 f16x8;
typedef __attribute__((ext_vector_type(4))) _Float16 f16x4;
typedef __attribute__((ext_vector_type(4))) float f32x4;

// ---------------- CSR build ----------------
__global__ void k_zero_int(int* __restrict__ p, int n) {
  int i = blockIdx.x * blockDim.x + threadIdx.x;
  if (i < n) p[i] = 0;
}

__global__ void k_count(const int* __restrict__ dst, int* __restrict__ counts, int e) {
  int i = blockIdx.x * blockDim.x + threadIdx.x;
  if (i < e) atomicAdd(&counts[dst[i]], 1);
}

__global__ __launch_bounds__(256) void k_scan_part(
    const int* __restrict__ counts, int* __restrict__ bsums, int n) {
  int tid = threadIdx.x;
  int i0 = blockIdx.x * 1024 + tid * 4;
  int s = 0;
#pragma unroll
  for (int k = 0; k < 4; k++) { int i = i0 + k; if (i < n) s += counts[i]; }
#pragma unroll
  for (int d = 1; d < 64; d <<= 1) s += __shfl_xor(s, d);
  __shared__ int wsum[4];
  int lane = tid & 63, w = tid >> 6;
  if (lane == 0) wsum[w] = s;
  __syncthreads();
  if (tid == 0) bsums[blockIdx.x] = wsum[0] + wsum[1] + wsum[2] + wsum[3];
}

__global__ __launch_bounds__(128) void k_scan_top(int* __restrict__ bsums, int nb) {
  int tid = threadIdx.x;
  int orig = (tid < nb) ? bsums[tid] : 0;
  int v = orig;
  int lane = tid & 63, w = tid >> 6;
#pragma unroll
  for (int d = 1; d < 64; d <<= 1) { int t = __shfl_up(v, d); if (lane >= d) v += t; }
  __shared__ int ws[2];
  if (lane == 63) ws[w] = v;
  __syncthreads();
  if (w == 1) v += ws[0];
  if (tid < nb) bsums[tid] = v - orig;  // exclusive
}

__global__ __launch_bounds__(256) void k_scan_down(
    const int* __restrict__ counts, const int* __restrict__ bsums,
    int* __restrict__ offsets, float* __restrict__ dinv, int n, int e) {
  int tid = threadIdx.x;
  int i0 = blockIdx.x * 1024 + tid * 4;
  int c[4]; int tsum = 0;
#pragma unroll
  for (int k = 0; k < 4; k++) { int i = i0 + k; c[k] = (i < n) ? counts[i] : 0; tsum += c[k]; }
  int v = tsum;
  int lane = tid & 63, w = tid >> 6;
#pragma unroll
  for (int d = 1; d < 64; d <<= 1) { int t = __shfl_up(v, d); if (lane >= d) v += t; }
  __shared__ int wsum[4];
  if (lane == 63) wsum[w] = v;
  __syncthreads();
  int wadd = 0;
#pragma unroll
  for (int q = 0; q < 4; q++) if (q < w) wadd += wsum[q];
  int run = (v - tsum) + wadd + bsums[blockIdx.x];
#pragma unroll
  for (int k = 0; k < 4; k++) {
    int i = i0 + k;
    if (i < n) { offsets[i] = run; dinv[i] = rsqrtf((float)(c[k] + 1)); }
    run += c[k];
  }
  if (blockIdx.x == 0 && tid == 0) offsets[n] = e;
}

// packed edge record: {src, norm as bits} -> one 8B meta load in gather
__global__ void k_fill(const int* __restrict__ src, const int* __restrict__ dst,
                       const int* __restrict__ offsets, int* __restrict__ cursor,
                       const float* __restrict__ dinv, int2* __restrict__ csr, int e) {
  int i = blockIdx.x * blockDim.x + threadIdx.x;
  if (i >= e) return;
  int s = src[i], d = dst[i];
  int pos = atomicAdd(&cursor[d], 1);
  csr[offsets[d] + pos] = make_int2(s, __float_as_int(dinv[s] * dinv[d]));
}

// ---------------- weight prepack (fragment-ordered fp16 hi/lo) ----------------
// B fragment for mfma_f32_16x16x32_f16: lane l holds B[ks*32+(l>>4)*8+i][ct*16+(l&15)]
// hi/lo layout: elem[((ks*CT+ct)*2+h)*512 + lane*8 + i]; hi-only: [(ks*CT+ct)*512 + ...]
__device__ __forceinline__ void pack_hi(const float* __restrict__ W,
                                        _Float16* __restrict__ dst,
                                        int K, int N, int u) {
  int lane = u & 63; int rest = u >> 6; int CT = N >> 4;
  int ct = rest % CT, ks = rest / CT;
  int gcol = ct * 16 + (lane & 15);
  int gk0 = ks * 32 + (lane >> 4) * 8;
  size_t o = (size_t)(ks * CT + ct) * 512 + lane * 8;
#pragma unroll
  for (int i = 0; i < 8; i++) {
    float v = (gk0 + i < K) ? W[(size_t)(gk0 + i) * N + gcol] : 0.0f;
    dst[o + i] = (_Float16)v;
  }
}

__device__ __forceinline__ void pack_hl(const float* __restrict__ W,
                                        _Float16* __restrict__ dst,
                                        int K, int N, int u) {
  int lane = u & 63; int rest = u >> 6; int CT = N >> 4;
  int ct = rest % CT, ks = rest / CT;
  int gcol = ct * 16 + (lane & 15);
  int gk0 = ks * 32 + (lane >> 4) * 8;
  size_t oh = (size_t)((ks * CT + ct) * 2) * 512 + lane * 8;
#pragma unroll
  for (int i = 0; i < 8; i++) {
    float v = (gk0 + i < K) ? W[(size_t)(gk0 + i) * N + gcol] : 0.0f;
    _Float16 h = (_Float16)v;
    dst[oh + i] = h;
    dst[oh + 512 + i] = (_Float16)(v - (float)h);
  }
}

// units: Wi(hi) 6*8*64=3072 | Wg1 4*8*64=2048 | Wg2 4*4*64=1024 | Wg3 2*2*64=256
__global__ void k_prepack(const float* __restrict__ Wi, const float* __restrict__ Wg1,
                          const float* __restrict__ Wg2, const float* __restrict__ Wg3,
                          _Float16* __restrict__ pWi, _Float16* __restrict__ pWg1,
                          _Float16* __restrict__ pWg2, _Float16* __restrict__ pWg3) {
  int t = blockIdx.x * blockDim.x + threadIdx.x;
  if (t < 3072) pack_hi(Wi, pWi, 164, 128, t);
  else if (t < 5120) pack_hl(Wg1, pWg1, 128, 128, t - 3072);
  else if (t < 6144) pack_hl(Wg2, pWg2, 128, 64, t - 5120);
  else if (t < 6400) pack_hl(Wg3, pWg3, 64, 32, t - 6144);
}

// ---------------- input GEMM: h = LN(relu(x@Wi+bi)) ----------------
// 512 thr / 8 waves, 128 rows per block. x f32 split to fp16 hi/lo (exact to
// 2^-22); Wi hi-only fp16 in LDS (48KB, staged once). 2 MFMAs per tile.
__global__ __launch_bounds__(512) void k_gemm_in(
    const float* __restrict__ x, const _Float16* __restrict__ pB,
    const float* __restrict__ bias, const float* __restrict__ gamma,
    const float* __restrict__ beta, _Float16* __restrict__ out, int n) {
  constexpr int K = 164, N = 128, KS = 6, CT = 8;
  __shared__ __align__(16) _Float16 sB[KS * CT * 512];  // 48 KB
  int tid = threadIdx.x;
  {
    const f16x8* s = (const f16x8*)pB;
    f16x8* d = (f16x8*)sB;
    for (int i = tid; i < KS * CT * 64; i += 512) d[i] = s[i];
  }
  __syncthreads();
  int lane = tid & 63, w = tid >> 6;
  int row = blockIdx.x * 128 + w * 16 + (lane & 15);
  bool rv = row < n;
  const float* ar = x + (size_t)row * K;
  int kof = (lane >> 4) * 8;
  f32x4 acc[CT];
#pragma unroll
  for (int c = 0; c < CT; c++) acc[c] = (f32x4)0.0f;
  for (int ks = 0; ks < KS; ks++) {
    int gk = ks * 32 + kof;
    float v[8];
    if (rv && gk + 8 <= K) {
      const float4* p = (const float4*)(ar + gk);
      float4 u0 = p[0], u1 = p[1];
      v[0] = u0.x; v[1] = u0.y; v[2] = u0.z; v[3] = u0.w;
      v[4] = u1.x; v[5] = u1.y; v[6] = u1.z; v[7] = u1.w;
    } else {
#pragma unroll
      for (int i = 0; i < 8; i++) v[i] = (rv && gk + i < K) ? ar[gk + i] : 0.0f;
    }
    f16x8 ah, al;
#pragma unroll
    for (int i = 0; i < 8; i++) {
      ah[i] = (_Float16)v[i];
      al[i] = (_Float16)(v[i] - (float)ah[i]);
    }
#pragma unroll
    for (int c = 0; c < CT; c++) {
      f16x8 b = ((const f16x8*)sB)[(ks * CT + c) * 64 + lane];
      acc[c] = __builtin_amdgcn_mfma_f32_16x16x32_f16(ah, b, acc[c], 0, 0, 0);
      acc[c] = __builtin_amdgcn_mfma_f32_16x16x32_f16(al, b, acc[c], 0, 0, 0);
    }
  }
  // bias + relu + LN over N cols (row lives in a 16-lane group)
  int r0 = (lane >> 4) * 4;
  int li = lane & 15;
  float s1[4] = {0, 0, 0, 0}, s2[4] = {0, 0, 0, 0};
#pragma unroll
  for (int c = 0; c < CT; c++) {
    float bb = bias[c * 16 + li];
#pragma unroll
    for (int r = 0; r < 4; r++) {
      float t = acc[c][r] + bb;
      t = t > 0.0f ? t : 0.0f;
      acc[c][r] = t;
      s1[r] += t;
      s2[r] += t * t;
    }
  }
#pragma unroll
  for (int m = 1; m < 16; m <<= 1) {
#pragma unroll
    for (int r = 0; r < 4; r++) {
      s1[r] += __shfl_xor(s1[r], m);
      s2[r] += __shfl_xor(s2[r], m);
    }
  }
#pragma unroll
  for (int c = 0; c < CT; c++) {
    float gv = gamma[c * 16 + li], bv = beta[c * 16 + li];
#pragma unroll
    for (int r = 0; r < 4; r++) {
      int node = blockIdx.x * 128 + w * 16 + r0 + r;
      if (node < n) {
        float mean = s1[r] * (1.0f / N);
        float var = s2[r] * (1.0f / N) - mean * mean;
        float rs = rsqrtf(var + 1e-5f);
        out[(size_t)node * N + c * 16 + li] =
            (_Float16)((acc[c][r] - mean) * rs * gv + bv);
      }
    }
  }
}

// ---------------- conv GEMM: xw = A@W (A exact fp16, W hi/lo fp16) ----------
template <int K, int N>
__global__ __launch_bounds__(512) void k_gemm_f16(
    const _Float16* __restrict__ A, const _Float16* __restrict__ pB,
    _Float16* __restrict__ out, int n) {
  constexpr int KS = K / 32, CT = N / 16;
  __shared__ __align__(16) _Float16 sB[KS * CT * 1024];  // <=64 KB (conv1)
  int tid = threadIdx.x;
  {
    const f16x8* s = (const f16x8*)pB;
    f16x8* d = (f16x8*)sB;
    for (int i = tid; i < KS * CT * 128; i += 512) d[i] = s[i];
  }
  __syncthreads();
  int lane = tid & 63, w = tid >> 6;
  int row = blockIdx.x * 128 + w * 16 + (lane & 15);
  bool rv = row < n;
  const _Float16* ar = A + (size_t)row * K + (lane >> 4) * 8;
  f32x4 acc[CT];
#pragma unroll
  for (int c = 0; c < CT; c++) acc[c] = (f32x4)0.0f;
  for (int ks = 0; ks < KS; ks++) {
    f16x8 av;
    if (rv) av = *(const f16x8*)(ar + ks * 32);
    else {
#pragma unroll
      for (int i = 0; i < 8; i++) av[i] = (_Float16)0.0f;
    }
#pragma unroll
    for (int c = 0; c < CT; c++) {
      f16x8 bh = ((const f16x8*)sB)[((ks * CT + c) * 2) * 64 + lane];
      f16x8 bl = ((const f16x8*)sB)[((ks * CT + c) * 2 + 1) * 64 + lane];
      acc[c] = __builtin_amdgcn_mfma_f32_16x16x32_f16(av, bh, acc[c], 0, 0, 0);
      acc[c] = __builtin_amdgcn_mfma_f32_16x16x32_f16(av, bl, acc[c], 0, 0, 0);
    }
  }
  int r0 = (lane >> 4) * 4;
  int li = lane & 15;
#pragma unroll
  for (int c = 0; c < CT; c++) {
#pragma unroll
    for (int r = 0; r < 4; r++) {
      int node = blockIdx.x * 128 + w * 16 + r0 + r;
      if (node < n) out[(size_t)node * N + c * 16 + li] = (_Float16)acc[c][r];
    }
  }
}

// ---------------- dst-side gather, 4 cols/thread, 4x-unrolled edges --------
// MODE 0: out = relu(agg) + auxh[node]      (conv1)
// MODE 1: out = LN(relu(agg); gamma, beta)  (conv2)
// MODE 2: out = agg                         (conv3; tail applies relu)
template <int OUT_D, int MODE>
__global__ __launch_bounds__(256) void k_gather(
    const int* __restrict__ off, const int2* __restrict__ csr,
    const _Float16* __restrict__ xw, const float* __restrict__ dinv,
    const float* __restrict__ bias, const _Float16* __restrict__ auxh,
    const float* __restrict__ gamma, const float* __restrict__ beta,
    _Float16* __restrict__ out, int n) {
  constexpr int TPN = OUT_D / 4;   // threads per node
  constexpr int NPB = 256 / TPN;
  int tid = threadIdx.x;
  int node = blockIdx.x * NPB + tid / TPN;
  int li = tid % TPN;
  if (node >= n) return;
  int start = off[node], end = off[node + 1];
  float di = dinv[node];
  float d2 = di * di;
  const _Float16* xp = xw + 4 * li;
  f16x4 self = *(const f16x4*)(xp + (size_t)node * OUT_D);
  float a0 = (float)self[0] * d2 + bias[4 * li + 0];
  float a1 = (float)self[1] * d2 + bias[4 * li + 1];
  float a2 = (float)self[2] * d2 + bias[4 * li + 2];
  float a3 = (float)self[3] * d2 + bias[4 * li + 3];
  for (int base = start; base < end; base += TPN) {
    int m = end - base; if (m > TPN) m = TPN;
    int sv = 0; float nv = 0.0f;
    if (li < m) { int2 me = csr[base + li]; sv = me.x; nv = __int_as_float(me.y); }
    int j = 0;
    for (; j + 4 <= m; j += 4) {  // 4 gather loads in flight
      int s0 = __shfl(sv, j + 0, TPN); float w0 = __shfl(nv, j + 0, TPN);
      int s1 = __shfl(sv, j + 1, TPN); float w1 = __shfl(nv, j + 1, TPN);
      int s2 = __shfl(sv, j + 2, TPN); float w2 = __shfl(nv, j + 2, TPN);
      int s3 = __shfl(sv, j + 3, TPN); float w3 = __shfl(nv, j + 3, TPN);
      f16x4 v0 = *(const f16x4*)(xp + (size_t)s0 * OUT_D);
      f16x4 v1 = *(const f16x4*)(xp + (size_t)s1 * OUT_D);
      f16x4 v2 = *(const f16x4*)(xp + (size_t)s2 * OUT_D);
      f16x4 v3 = *(const f16x4*)(xp + (size_t)s3 * OUT_D);
      a0 += (float)v0[0] * w0 + (float)v1[0] * w1 + (float)v2[0] * w2 + (float)v3[0] * w3;
      a1 += (float)v0[1] * w0 + (float)v1[1] * w1 + (float)v2[1] * w2 + (float)v3[1] * w3;
      a2 += (float)v0[2] * w0 + (float)v1[2] * w1 + (float)v2[2] * w2 + (float)v3[2] * w3;
      a3 += (float)v0[3] * w0 + (float)v1[3] * w1 + (float)v2[3] * w2 + (float)v3[3] * w3;
    }
    for (; j < m; j++) {
      int s = __shfl(sv, j, TPN); float wj = __shfl(nv, j, TPN);
      f16x4 v = *(const f16x4*)(xp + (size_t)s * OUT_D);
      a0 += (float)v[0] * wj; a1 += (float)v[1] * wj;
      a2 += (float)v[2] * wj; a3 += (float)v[3] * wj;
    }
  }
  _Float16* po = out + (size_t)node * OUT_D + 4 * li;
  if constexpr (MODE == 0) {
    f16x4 hres = *(const f16x4*)(auxh + (size_t)node * OUT_D + 4 * li);
    f16x4 o;
    o[0] = (_Float16)((a0 > 0.0f ? a0 : 0.0f) + (float)hres[0]);
    o[1] = (_Float16)((a1 > 0.0f ? a1 : 0.0f) + (float)hres[1]);
    o[2] = (_Float16)((a2 > 0.0f ? a2 : 0.0f) + (float)hres[2]);
    o[3] = (_Float16)((a3 > 0.0f ? a3 : 0.0f) + (float)hres[3]);
    *(f16x4*)po = o;
  } else if constexpr (MODE == 1) {
    float v0 = a0 > 0.0f ? a0 : 0.0f, v1 = a1 > 0.0f ? a1 : 0.0f;
    float v2 = a2 > 0.0f ? a2 : 0.0f, v3 = a3 > 0.0f ? a3 : 0.0f;
    float s1 = v0 + v1 + v2 + v3;
    float s2 = v0 * v0 + v1 * v1 + v2 * v2 + v3 * v3;
#pragma unroll
    for (int d = 1; d < TPN; d <<= 1) {
      s1 += __shfl_xor(s1, d, TPN);
      s2 += __shfl_xor(s2, d, TPN);
    }
    float m_ = s1 * (1.0f / OUT_D);
    float var = s2 * (1.0f / OUT_D) - m_ * m_;
    float rs = rsqrtf(var + 1e-5f);
    f16x4 o;
    o[0] = (_Float16)((v0 - m_) * rs * gamma[4 * li + 0] + beta[4 * li + 0]);
    o[1] = (_Float16)((v1 - m_) * rs * gamma[4 * li + 1] + beta[4 * li + 1]);
    o[2] = (_Float16)((v2 - m_) * rs * gamma[4 * li + 2] + beta[4 * li + 2]);
    o[3] = (_Float16)((v3 - m_) * rs * gamma[4 * li + 3] + beta[4 * li + 3]);
    *(f16x4*)po = o;
  } else {
    f16x4 o;
    o[0] = (_Float16)a0; o[1] = (_Float16)a1;
    o[2] = (_Float16)a2; o[3] = (_Float16)a3;
    *(f16x4*)po = o;
  }
}

// ---------------- tail: relu(agg3) -> Wv -> Wo -> Wc1 -> Wc2 -> Wc3 --------
// (MHA with seq_len==1: softmax over one key == 1, so out = (x@Wv+bv)@Wo+bo)
__global__ __launch_bounds__(256) void k_tail(
    const _Float16* __restrict__ agg3, const float* __restrict__ Wv,
    const float* __restrict__ bv, const float* __restrict__ Wo,
    const float* __restrict__ bo, const float* __restrict__ Wc1,
    const float* __restrict__ bc1, const float* __restrict__ Wc2,
    const float* __restrict__ bc2, const float* __restrict__ Wc3,
    const float* __restrict__ bc3, float* __restrict__ out, int n) {
  __shared__ float sWv[1024], sWo[1024], sWc1[512], sWc2[512];
  __shared__ float sbv[32], sbo[32], sbc2[32], sWc3[32], sbc1[16], sbc3[1];
  int tid = threadIdx.x;
  for (int i = tid; i < 1024; i += 256) { sWv[i] = Wv[i]; sWo[i] = Wo[i]; }
  for (int i = tid; i < 512; i += 256) { sWc1[i] = Wc1[i]; sWc2[i] = Wc2[i]; }
  if (tid < 32) { sbv[tid] = bv[tid]; sbo[tid] = bo[tid];
                  sbc2[tid] = bc2[tid]; sWc3[tid] = Wc3[tid]; }
  if (tid < 16) sbc1[tid] = bc1[tid];
  if (tid == 0) sbc3[0] = bc3[0];
  __syncthreads();
  int node = blockIdx.x * blockDim.x + tid;
  if (node >= n) return;
  float a[32];
  const f16x8* row8 = (const f16x8*)(agg3 + (size_t)node * 32);
#pragma unroll
  for (int q = 0; q < 4; q++) {
    f16x8 t = row8[q];
#pragma unroll
    for (int i = 0; i < 8; i++) {
      float f = (float)t[i];
      a[8 * q + i] = f > 0.0f ? f : 0.0f;
    }
  }
  float v[32];
#pragma unroll
  for (int j = 0; j < 32; j++) v[j] = sbv[j];
  for (int k = 0; k < 32; k++) {
#pragma unroll
    for (int j = 0; j < 32; j++) v[j] += a[k] * sWv[k * 32 + j];
  }
  float o[32];
#pragma unroll
  for (int j = 0; j < 32; j++) o[j] = sbo[j];
  for (int k = 0; k < 32; k++) {
#pragma unroll
    for (int j = 0; j < 32; j++) o[j] += v[k] * sWo[k * 32 + j];
  }
  float c1[16];
#pragma unroll
  for (int j = 0; j < 16; j++) c1[j] = sbc1[j];
  for (int k = 0; k < 32; k++) {
#pragma unroll
    for (int j = 0; j < 16; j++) c1[j] += o[k] * sWc1[k * 16 + j];
  }
#pragma unroll
  for (int j = 0; j < 16; j++) c1[j] = c1[j] > 0.0f ? c1[j] : 0.0f;
  float c2[32];
#pragma unroll
  for (int j = 0; j < 32; j++) c2[j] = sbc2[j];
  for (int k = 0; k < 16; k++) {
#pragma unroll
    for (int j = 0; j < 32; j++) c2[j] += c1[k] * sWc2[k * 32 + j];
  }
  float r = sbc3[0];
#pragma unroll
  for (int k = 0; k < 32; k++) {
    float c = c2[k] > 0.0f ? c2[k] : 0.0f;
    r += c * sWc3[k];
  }
  out[node] = r;
}

// ---------------------------------------------------------------------------
extern "C" void kernel_launch(void* const* d_in, const int* in_sizes, int n_in,
                              void* d_out, int out_size, void* d_ws, size_t ws_size,
                              hipStream_t stream) {
  const float* x   = (const float*)d_in[0];
  const int* ei    = (const int*)d_in[1];
  const float* Wi  = (const float*)d_in[2];
  const float* bi  = (const float*)d_in[3];
  const float* g1  = (const float*)d_in[4];
  const float* b1  = (const float*)d_in[5];
  const float* Wg1 = (const float*)d_in[6];
  const float* bg1 = (const float*)d_in[7];
  const float* Wg2 = (const float*)d_in[8];
  const float* bg2 = (const float*)d_in[9];
  const float* g2  = (const float*)d_in[10];
  const float* b2  = (const float*)d_in[11];
  const float* Wg3 = (const float*)d_in[12];
  const float* bg3 = (const float*)d_in[13];
  // d_in[14..17]: Wq,bq,Wk,bk — mathematically dead (softmax over 1 key == 1)
  const float* Wv  = (const float*)d_in[18];
  const float* bv  = (const float*)d_in[19];
  const float* Wo  = (const float*)d_in[20];
  const float* bo  = (const float*)d_in[21];
  const float* Wc1 = (const float*)d_in[22];
  const float* bc1 = (const float*)d_in[23];
  const float* Wc2 = (const float*)d_in[24];
  const float* bc2 = (const float*)d_in[25];
  const float* Wc3 = (const float*)d_in[26];
  const float* bc3 = (const float*)d_in[27];

  const int n = in_sizes[0] / 164;
  const int e = in_sizes[1] / 2;
  const int* src = ei;
  const int* dst = ei + e;

  // workspace layout (256B aligned)
  char* ws = (char*)d_ws;
  size_t off = 0;
  auto alloc = [&](size_t bytes) {
    char* p = ws + off;
    off += (bytes + 255) & ~(size_t)255;
    return p;
  };
  _Float16* A     = (_Float16*)alloc((size_t)n * 128 * 2);
  _Float16* B     = (_Float16*)alloc((size_t)n * 128 * 2);
  _Float16* C     = (_Float16*)alloc((size_t)n * 128 * 2);
  float* dinv     = (float*)alloc((size_t)n * 4);
  int*   counts   = (int*)alloc((size_t)n * 4);      // reused as fill cursor
  int*   offsets  = (int*)alloc((size_t)(n + 1) * 4);
  int*   bsums    = (int*)alloc(128 * 4);
  int2*  csr      = (int2*)alloc((size_t)e * 8);
  _Float16* pWi   = (_Float16*)alloc(6 * 8 * 512 * 2);       // 48 KB, hi only
  _Float16* pWg1  = (_Float16*)alloc(4 * 8 * 1024 * 2);      // 64 KB hi/lo
  _Float16* pWg2  = (_Float16*)alloc(4 * 4 * 1024 * 2);      // 32 KB
  _Float16* pWg3  = (_Float16*)alloc(2 * 2 * 1024 * 2);      // 8 KB
  (void)ws_size;

  const int BS = 256;
  const int SB = (n + 1023) / 1024;  // scan blocks (98 for n=100k, <=128)
  const int GB = (n + 127) / 128;    // gemm blocks (512 thr, 128 rows)

  // ---- weight prepack (independent of everything else) ----
  k_prepack<<<25, 256, 0, stream>>>(Wi, Wg1, Wg2, Wg3, pWi, pWg1, pWg2, pWg3);

  // ---- CSR build (shared by all three convs) ----
  k_zero_int<<<(n + BS - 1) / BS, BS, 0, stream>>>(counts, n);
  k_count<<<(e + BS - 1) / BS, BS, 0, stream>>>(dst, counts, e);
  k_scan_part<<<SB, 256, 0, stream>>>(counts, bsums, n);
  k_scan_top<<<1, 128, 0, stream>>>(bsums, SB);
  k_scan_down<<<SB, 256, 0, stream>>>(counts, bsums, offsets, dinv, n, e);
  k_zero_int<<<(n + BS - 1) / BS, BS, 0, stream>>>(counts, n);  // cursor
  k_fill<<<(e + BS - 1) / BS, BS, 0, stream>>>(src, dst, offsets, counts, dinv,
                                               csr, e);

  // ---- input layer: A = h = LN(relu(x@Wi+bi))  [fp16] ----
  k_gemm_in<<<GB, 512, 0, stream>>>(x, pWi, bi, g1, b1, A, n);

  // ---- conv1: B = xw1 = h@Wg1; gather -> C = h1 = relu(agg)+h ----
  k_gemm_f16<128, 128><<<GB, 512, 0, stream>>>(A, pWg1, B, n);
  k_gather<128, 0><<<(n + 7) / 8, 256, 0, stream>>>(
      offsets, csr, B, dinv, bg1, A, nullptr, nullptr, C, n);

  // ---- conv2: A = xw2 = h1@Wg2 [n,64]; gather -> B = h2 = LN(relu(agg)) ----
  k_gemm_f16<128, 64><<<GB, 512, 0, stream>>>(C, pWg2, A, n);
  k_gather<64, 1><<<(n + 15) / 16, 256, 0, stream>>>(
      offsets, csr, A, dinv, bg2, nullptr, g2, b2, B, n);

  // ---- conv3: A = xw3 = h2@Wg3 [n,32]; gather -> C = agg3 [fp16] ----
  k_gemm_f16<64, 32><<<GB, 512, 0, stream>>>(B, pWg3, A, n);
  k_gather<32, 2><<<(n + 31) / 32, 256, 0, stream>>>(
      offsets, csr, A, dinv, bg3, nullptr, nullptr, nullptr, C, n);

  // ---- tail: relu(agg3) -> MHA(v,o) -> MLP -> out ----
  k_tail<<<(n + BS - 1) / BS, BS, 0, stream>>>(
      C, Wv, bv, Wo, bo, Wc1, bc1, Wc2, bc2, Wc3, bc3, (float*)d_out, n);
}

// Round 7
// 227.323 us; speedup vs baseline: 5.2874x; 1.0333x over previous
//
#include <hip/hip_runtime.h>

// ---------------------------------------------------------------------------
// EnhancedBitcoinGCN: 3x GCNConv + LN/residual + (trivial) MHA + MLP head
// N=100000 nodes, E=600000 edges, dims 164->128->128->64->32->16->32->1
// Round 6 -> 7 (latency + launch-count round):
//  * k_gemm_in: hoist ALL x loads (11 float4/thread in flight, was ~2) ->
//    attacks 39-45us @ 21% VALUBusy latency-bound top kernel.
//  * gather: branch-free 8-deep load batches; idle lanes padded with
//    {node, w=0} so loads always issue 8 back-to-back (self row is L1-hot).
//  * k_gemm_f16: A-fragment loads hoisted above MFMA loop.
//  * launches 17 -> 14: prepack+zero fused (k_setup); cursor zeroed inside
//    k_scan_down (same-thread read-then-zero of counts).
// ---------------------------------------------------------------------------

typedef __attribute__((ext_vector_type(8))) _Float16 f16x8;
typedef __attribute__((ext_vector_type(4))) _Float16 f16x4;
typedef __attribute__((ext_vector_type(4))) float f32x4;

// ---------------- CSR build ----------------
__global__ void k_count(const int* __restrict__ dst, int* __restrict__ counts, int e) {
  int i = blockIdx.x * blockDim.x + threadIdx.x;
  if (i < e) atomicAdd(&counts[dst[i]], 1);
}

__global__ __launch_bounds__(256) void k_scan_part(
    const int* __restrict__ counts, int* __restrict__ bsums, int n) {
  int tid = threadIdx.x;
  int i0 = blockIdx.x * 1024 + tid * 4;
  int s = 0;
#pragma unroll
  for (int k = 0; k < 4; k++) { int i = i0 + k; if (i < n) s += counts[i]; }
#pragma unroll
  for (int d = 1; d < 64; d <<= 1) s += __shfl_xor(s, d);
  __shared__ int wsum[4];
  int lane = tid & 63, w = tid >> 6;
  if (lane == 0) wsum[w] = s;
  __syncthreads();
  if (tid == 0) bsums[blockIdx.x] = wsum[0] + wsum[1] + wsum[2] + wsum[3];
}

__global__ __launch_bounds__(128) void k_scan_top(int* __restrict__ bsums, int nb) {
  int tid = threadIdx.x;
  int orig = (tid < nb) ? bsums[tid] : 0;
  int v = orig;
  int lane = tid & 63, w = tid >> 6;
#pragma unroll
  for (int d = 1; d < 64; d <<= 1) { int t = __shfl_up(v, d); if (lane >= d) v += t; }
  __shared__ int ws[2];
  if (lane == 63) ws[w] = v;
  __syncthreads();
  if (w == 1) v += ws[0];
  if (tid < nb) bsums[tid] = v - orig;  // exclusive
}

// offsets + dinv + (counts -> 0, becoming the fill cursor)
__global__ __launch_bounds__(256) void k_scan_down(
    int* __restrict__ counts, const int* __restrict__ bsums,
    int* __restrict__ offsets, float* __restrict__ dinv, int n, int e) {
  int tid = threadIdx.x;
  int i0 = blockIdx.x * 1024 + tid * 4;
  int c[4]; int tsum = 0;
#pragma unroll
  for (int k = 0; k < 4; k++) { int i = i0 + k; c[k] = (i < n) ? counts[i] : 0; tsum += c[k]; }
  int v = tsum;
  int lane = tid & 63, w = tid >> 6;
#pragma unroll
  for (int d = 1; d < 64; d <<= 1) { int t = __shfl_up(v, d); if (lane >= d) v += t; }
  __shared__ int wsum[4];
  if (lane == 63) wsum[w] = v;
  __syncthreads();
  int wadd = 0;
#pragma unroll
  for (int q = 0; q < 4; q++) if (q < w) wadd += wsum[q];
  int run = (v - tsum) + wadd + bsums[blockIdx.x];
#pragma unroll
  for (int k = 0; k < 4; k++) {
    int i = i0 + k;
    if (i < n) {
      offsets[i] = run;
      dinv[i] = rsqrtf((float)(c[k] + 1));
      counts[i] = 0;  // becomes fill cursor
    }
    run += c[k];
  }
  if (blockIdx.x == 0 && tid == 0) offsets[n] = e;
}

// packed edge record: {src, norm as bits} -> one 8B meta load in gather
__global__ void k_fill(const int* __restrict__ src, const int* __restrict__ dst,
                       const int* __restrict__ offsets, int* __restrict__ cursor,
                       const float* __restrict__ dinv, int2* __restrict__ csr, int e) {
  int i = blockIdx.x * blockDim.x + threadIdx.x;
  if (i >= e) return;
  int s = src[i], d = dst[i];
  int pos = atomicAdd(&cursor[d], 1);
  csr[offsets[d] + pos] = make_int2(s, __float_as_int(dinv[s] * dinv[d]));
}

// ---------------- weight prepack (fragment-ordered fp16 hi/lo) -------------
// B fragment for mfma_f32_16x16x32_f16: lane l holds B[ks*32+(l>>4)*8+i][ct*16+(l&15)]
__device__ __forceinline__ void pack_hi(const float* __restrict__ W,
                                        _Float16* __restrict__ dst,
                                        int K, int N, int u) {
  int lane = u & 63; int rest = u >> 6; int CT = N >> 4;
  int ct = rest % CT, ks = rest / CT;
  int gcol = ct * 16 + (lane & 15);
  int gk0 = ks * 32 + (lane >> 4) * 8;
  size_t o = (size_t)(ks * CT + ct) * 512 + lane * 8;
#pragma unroll
  for (int i = 0; i < 8; i++) {
    float v = (gk0 + i < K) ? W[(size_t)(gk0 + i) * N + gcol] : 0.0f;
    dst[o + i] = (_Float16)v;
  }
}

__device__ __forceinline__ void pack_hl(const float* __restrict__ W,
                                        _Float16* __restrict__ dst,
                                        int K, int N, int u) {
  int lane = u & 63; int rest = u >> 6; int CT = N >> 4;
  int ct = rest % CT, ks = rest / CT;
  int gcol = ct * 16 + (lane & 15);
  int gk0 = ks * 32 + (lane >> 4) * 8;
  size_t oh = (size_t)((ks * CT + ct) * 2) * 512 + lane * 8;
#pragma unroll
  for (int i = 0; i < 8; i++) {
    float v = (gk0 + i < K) ? W[(size_t)(gk0 + i) * N + gcol] : 0.0f;
    _Float16 h = (_Float16)v;
    dst[oh + i] = h;
    dst[oh + 512 + i] = (_Float16)(v - (float)h);
  }
}

// blocks [0,25): prepack (6400 units); blocks [25,..): zero counts
__global__ void k_setup(const float* __restrict__ Wi, const float* __restrict__ Wg1,
                        const float* __restrict__ Wg2, const float* __restrict__ Wg3,
                        _Float16* __restrict__ pWi, _Float16* __restrict__ pWg1,
                        _Float16* __restrict__ pWg2, _Float16* __restrict__ pWg3,
                        int* __restrict__ counts, int n) {
  int b = blockIdx.x;
  if (b < 25) {
    int t = b * 256 + threadIdx.x;
    if (t < 3072) pack_hi(Wi, pWi, 164, 128, t);
    else if (t < 5120) pack_hl(Wg1, pWg1, 128, 128, t - 3072);
    else if (t < 6144) pack_hl(Wg2, pWg2, 128, 64, t - 5120);
    else if (t < 6400) pack_hl(Wg3, pWg3, 64, 32, t - 6144);
  } else {
    int i = (b - 25) * 256 + threadIdx.x;
    if (i < n) counts[i] = 0;
  }
}

// ---------------- input GEMM: h = LN(relu(x@Wi+bi)) ----------------
// 512 thr / 8 waves, 128 rows/block. All 11 float4 x-loads issued up front.
__global__ __launch_bounds__(512) void k_gemm_in(
    const float* __restrict__ x, const _Float16* __restrict__ pB,
    const float* __restrict__ bias, const float* __restrict__ gamma,
    const float* __restrict__ beta, _Float16* __restrict__ out, int n) {
  constexpr int K = 164, N = 128, CT = 8;
  __shared__ __align__(16) _Float16 sB[6 * CT * 512];  // 48 KB
  int tid = threadIdx.x;
  {
    const f16x8* s = (const f16x8*)pB;
    f16x8* d = (f16x8*)sB;
    for (int i = tid; i < 6 * CT * 64; i += 512) d[i] = s[i];
  }
  __syncthreads();
  int lane = tid & 63, w = tid >> 6;
  int row = blockIdx.x * 128 + w * 16 + (lane & 15);
  bool rv = row < n;
  int kof = (lane >> 4) * 8;
  // hoist all x loads: ks 0..4 full (2 float4 each), ks 5 only kof==0 (k=160..163)
  float4 xv[11];
#pragma unroll
  for (int i = 0; i < 11; i++) xv[i] = make_float4(0.f, 0.f, 0.f, 0.f);
  if (rv) {
    const float4* p = (const float4*)(x + (size_t)row * K + kof);
#pragma unroll
    for (int ks = 0; ks < 5; ks++) { xv[2 * ks] = p[ks * 8]; xv[2 * ks + 1] = p[ks * 8 + 1]; }
    if (kof == 0) xv[10] = *(const float4*)(x + (size_t)row * K + 160);
  }
  f32x4 acc[CT];
#pragma unroll
  for (int c = 0; c < CT; c++) acc[c] = (f32x4)0.0f;
#pragma unroll
  for (int ks = 0; ks < 6; ks++) {
    float v[8];
    if (ks < 5) {
      float4 u0 = xv[2 * ks], u1 = xv[2 * ks + 1];
      v[0] = u0.x; v[1] = u0.y; v[2] = u0.z; v[3] = u0.w;
      v[4] = u1.x; v[5] = u1.y; v[6] = u1.z; v[7] = u1.w;
    } else {
      float4 u0 = xv[10];
      v[0] = u0.x; v[1] = u0.y; v[2] = u0.z; v[3] = u0.w;
      v[4] = 0.f; v[5] = 0.f; v[6] = 0.f; v[7] = 0.f;
    }
    f16x8 ah, al;
#pragma unroll
    for (int i = 0; i < 8; i++) {
      ah[i] = (_Float16)v[i];
      al[i] = (_Float16)(v[i] - (float)ah[i]);
    }
#pragma unroll
    for (int c = 0; c < CT; c++) {
      f16x8 b = ((const f16x8*)sB)[(ks * CT + c) * 64 + lane];
      acc[c] = __builtin_amdgcn_mfma_f32_16x16x32_f16(ah, b, acc[c], 0, 0, 0);
      acc[c] = __builtin_amdgcn_mfma_f32_16x16x32_f16(al, b, acc[c], 0, 0, 0);
    }
  }
  // bias + relu + LN over N cols (row lives in a 16-lane group)
  int r0 = (lane >> 4) * 4;
  int li = lane & 15;
  float s1[4] = {0, 0, 0, 0}, s2[4] = {0, 0, 0, 0};
#pragma unroll
  for (int c = 0; c < CT; c++) {
    float bb = bias[c * 16 + li];
#pragma unroll
    for (int r = 0; r < 4; r++) {
      float t = acc[c][r] + bb;
      t = t > 0.0f ? t : 0.0f;
      acc[c][r] = t;
      s1[r] += t;
      s2[r] += t * t;
    }
  }
#pragma unroll
  for (int m = 1; m < 16; m <<= 1) {
#pragma unroll
    for (int r = 0; r < 4; r++) {
      s1[r] += __shfl_xor(s1[r], m);
      s2[r] += __shfl_xor(s2[r], m);
    }
  }
#pragma unroll
  for (int c = 0; c < CT; c++) {
    float gv = gamma[c * 16 + li], bv = beta[c * 16 + li];
#pragma unroll
    for (int r = 0; r < 4; r++) {
      int node = blockIdx.x * 128 + w * 16 + r0 + r;
      if (node < n) {
        float mean = s1[r] * (1.0f / N);
        float var = s2[r] * (1.0f / N) - mean * mean;
        float rs = rsqrtf(var + 1e-5f);
        out[(size_t)node * N + c * 16 + li] =
            (_Float16)((acc[c][r] - mean) * rs * gv + bv);
      }
    }
  }
}

// ---------------- conv GEMM: xw = A@W (A exact fp16, W hi/lo fp16) ----------
template <int K, int N>
__global__ __launch_bounds__(512) void k_gemm_f16(
    const _Float16* __restrict__ A, const _Float16* __restrict__ pB,
    _Float16* __restrict__ out, int n) {
  constexpr int KS = K / 32, CT = N / 16;
  __shared__ __align__(16) _Float16 sB[KS * CT * 1024];  // <=64 KB (conv1)
  int tid = threadIdx.x;
  {
    const f16x8* s = (const f16x8*)pB;
    f16x8* d = (f16x8*)sB;
    for (int i = tid; i < KS * CT * 128; i += 512) d[i] = s[i];
  }
  __syncthreads();
  int lane = tid & 63, w = tid >> 6;
  int row = blockIdx.x * 128 + w * 16 + (lane & 15);
  bool rv = row < n;
  const _Float16* ar = A + (size_t)row * K + (lane >> 4) * 8;
  // hoist all A-fragment loads
  f16x8 av[KS];
#pragma unroll
  for (int ks = 0; ks < KS; ks++) {
    if (rv) av[ks] = *(const f16x8*)(ar + ks * 32);
    else {
#pragma unroll
      for (int i = 0; i < 8; i++) av[ks][i] = (_Float16)0.0f;
    }
  }
  f32x4 acc[CT];
#pragma unroll
  for (int c = 0; c < CT; c++) acc[c] = (f32x4)0.0f;
#pragma unroll
  for (int ks = 0; ks < KS; ks++) {
#pragma unroll
    for (int c = 0; c < CT; c++) {
      f16x8 bh = ((const f16x8*)sB)[((ks * CT + c) * 2) * 64 + lane];
      f16x8 bl = ((const f16x8*)sB)[((ks * CT + c) * 2 + 1) * 64 + lane];
      acc[c] = __builtin_amdgcn_mfma_f32_16x16x32_f16(av[ks], bh, acc[c], 0, 0, 0);
      acc[c] = __builtin_amdgcn_mfma_f32_16x16x32_f16(av[ks], bl, acc[c], 0, 0, 0);
    }
  }
  int r0 = (lane >> 4) * 4;
  int li = lane & 15;
#pragma unroll
  for (int c = 0; c < CT; c++) {
#pragma unroll
    for (int r = 0; r < 4; r++) {
      int node = blockIdx.x * 128 + w * 16 + r0 + r;
      if (node < n) out[(size_t)node * N + c * 16 + li] = (_Float16)acc[c][r];
    }
  }
}

// ---------------- dst-side gather, 4 cols/thread, 8-deep load batches ------
// Idle meta lanes padded with {node, 0.0} -> inner loop is a branch-free
// batch of 8 shfl + 8 loads (padding loads hit the L1-hot self row, w=0).
// MODE 0: out = relu(agg) + auxh[node]      (conv1)
// MODE 1: out = LN(relu(agg); gamma, beta)  (conv2)
// MODE 2: out = agg                         (conv3; tail applies relu)
template <int OUT_D, int MODE>
__global__ __launch_bounds__(256) void k_gather(
    const int* __restrict__ off, const int2* __restrict__ csr,
    const _Float16* __restrict__ xw, const float* __restrict__ dinv,
    const float* __restrict__ bias, const _Float16* __restrict__ auxh,
    const float* __restrict__ gamma, const float* __restrict__ beta,
    _Float16* __restrict__ out, int n) {
  constexpr int TPN = OUT_D / 4;   // threads per node (32/16/8 - multiples of 8)
  constexpr int NPB = 256 / TPN;
  int tid = threadIdx.x;
  int node = blockIdx.x * NPB + tid / TPN;
  int li = tid % TPN;
  if (node >= n) return;
  int start = off[node], end = off[node + 1];
  float di = dinv[node];
  float d2 = di * di;
  const _Float16* xp = xw + 4 * li;
  f16x4 self = *(const f16x4*)(xp + (size_t)node * OUT_D);
  float a0 = (float)self[0] * d2 + bias[4 * li + 0];
  float a1 = (float)self[1] * d2 + bias[4 * li + 1];
  float a2 = (float)self[2] * d2 + bias[4 * li + 2];
  float a3 = (float)self[3] * d2 + bias[4 * li + 3];
  for (int cb = start; cb < end; cb += TPN) {
    int m = end - cb; if (m > TPN) m = TPN;
    int sv = node; float nv = 0.0f;                 // pad: self row, weight 0
    if (li < m) { int2 me = csr[cb + li]; sv = me.x; nv = __int_as_float(me.y); }
    for (int j0 = 0; j0 < m; j0 += 8) {
      int s[8]; float wg[8];
#pragma unroll
      for (int q = 0; q < 8; q++) {
        s[q] = __shfl(sv, j0 + q, TPN);
        wg[q] = __shfl(nv, j0 + q, TPN);
      }
      f16x4 v[8];
#pragma unroll
      for (int q = 0; q < 8; q++) v[q] = *(const f16x4*)(xp + (size_t)s[q] * OUT_D);
#pragma unroll
      for (int q = 0; q < 8; q++) {
        a0 += (float)v[q][0] * wg[q];
        a1 += (float)v[q][1] * wg[q];
        a2 += (float)v[q][2] * wg[q];
        a3 += (float)v[q][3] * wg[q];
      }
    }
  }
  _Float16* po = out + (size_t)node * OUT_D + 4 * li;
  if constexpr (MODE == 0) {
    f16x4 hres = *(const f16x4*)(auxh + (size_t)node * OUT_D + 4 * li);
    f16x4 o;
    o[0] = (_Float16)((a0 > 0.0f ? a0 : 0.0f) + (float)hres[0]);
    o[1] = (_Float16)((a1 > 0.0f ? a1 : 0.0f) + (float)hres[1]);
    o[2] = (_Float16)((a2 > 0.0f ? a2 : 0.0f) + (float)hres[2]);
    o[3] = (_Float16)((a3 > 0.0f ? a3 : 0.0f) + (float)hres[3]);
    *(f16x4*)po = o;
  } else if constexpr (MODE == 1) {
    float v0 = a0 > 0.0f ? a0 : 0.0f, v1 = a1 > 0.0f ? a1 : 0.0f;
    float v2 = a2 > 0.0f ? a2 : 0.0f, v3 = a3 > 0.0f ? a3 : 0.0f;
    float s1 = v0 + v1 + v2 + v3;
    float s2 = v0 * v0 + v1 * v1 + v2 * v2 + v3 * v3;
#pragma unroll
    for (int d = 1; d < TPN; d <<= 1) {
      s1 += __shfl_xor(s1, d, TPN);
      s2 += __shfl_xor(s2, d, TPN);
    }
    float m_ = s1 * (1.0f / OUT_D);
    float var = s2 * (1.0f / OUT_D) - m_ * m_;
    float rs = rsqrtf(var + 1e-5f);
    f16x4 o;
    o[0] = (_Float16)((v0 - m_) * rs * gamma[4 * li + 0] + beta[4 * li + 0]);
    o[1] = (_Float16)((v1 - m_) * rs * gamma[4 * li + 1] + beta[4 * li + 1]);
    o[2] = (_Float16)((v2 - m_) * rs * gamma[4 * li + 2] + beta[4 * li + 2]);
    o[3] = (_Float16)((v3 - m_) * rs * gamma[4 * li + 3] + beta[4 * li + 3]);
    *(f16x4*)po = o;
  } else {
    f16x4 o;
    o[0] = (_Float16)a0; o[1] = (_Float16)a1;
    o[2] = (_Float16)a2; o[3] = (_Float16)a3;
    *(f16x4*)po = o;
  }
}

// ---------------- tail: relu(agg3) -> Wv -> Wo -> Wc1 -> Wc2 -> Wc3 --------
// (MHA with seq_len==1: softmax over one key == 1, so out = (x@Wv+bv)@Wo+bo)
__global__ __launch_bounds__(256) void k_tail(
    const _Float16* __restrict__ agg3, const float* __restrict__ Wv,
    const float* __restrict__ bv, const float* __restrict__ Wo,
    const float* __restrict__ bo, const float* __restrict__ Wc1,
    const float* __restrict__ bc1, const float* __restrict__ Wc2,
    const float* __restrict__ bc2, const float* __restrict__ Wc3,
    const float* __restrict__ bc3, float* __restrict__ out, int n) {
  __shared__ float sWv[1024], sWo[1024], sWc1[512], sWc2[512];
  __shared__ float sbv[32], sbo[32], sbc2[32], sWc3[32], sbc1[16], sbc3[1];
  int tid = threadIdx.x;
  for (int i = tid; i < 1024; i += 256) { sWv[i] = Wv[i]; sWo[i] = Wo[i]; }
  for (int i = tid; i < 512; i += 256) { sWc1[i] = Wc1[i]; sWc2[i] = Wc2[i]; }
  if (tid < 32) { sbv[tid] = bv[tid]; sbo[tid] = bo[tid];
                  sbc2[tid] = bc2[tid]; sWc3[tid] = Wc3[tid]; }
  if (tid < 16) sbc1[tid] = bc1[tid];
  if (tid == 0) sbc3[0] = bc3[0];
  __syncthreads();
  int node = blockIdx.x * blockDim.x + tid;
  if (node >= n) return;
  float a[32];
  const f16x8* row8 = (const f16x8*)(agg3 + (size_t)node * 32);
#pragma unroll
  for (int q = 0; q < 4; q++) {
    f16x8 t = row8[q];
#pragma unroll
    for (int i = 0; i < 8; i++) {
      float f = (float)t[i];
      a[8 * q + i] = f > 0.0f ? f : 0.0f;
    }
  }
  float v[32];
#pragma unroll
  for (int j = 0; j < 32; j++) v[j] = sbv[j];
  for (int k = 0; k < 32; k++) {
#pragma unroll
    for (int j = 0; j < 32; j++) v[j] += a[k] * sWv[k * 32 + j];
  }
  float o[32];
#pragma unroll
  for (int j = 0; j < 32; j++) o[j] = sbo[j];
  for (int k = 0; k < 32; k++) {
#pragma unroll
    for (int j = 0; j < 32; j++) o[j] += v[k] * sWo[k * 32 + j];
  }
  float c1[16];
#pragma unroll
  for (int j = 0; j < 16; j++) c1[j] = sbc1[j];
  for (int k = 0; k < 32; k++) {
#pragma unroll
    for (int j = 0; j < 16; j++) c1[j] += o[k] * sWc1[k * 16 + j];
  }
#pragma unroll
  for (int j = 0; j < 16; j++) c1[j] = c1[j] > 0.0f ? c1[j] : 0.0f;
  float c2[32];
#pragma unroll
  for (int j = 0; j < 32; j++) c2[j] = sbc2[j];
  for (int k = 0; k < 16; k++) {
#pragma unroll
    for (int j = 0; j < 32; j++) c2[j] += c1[k] * sWc2[k * 32 + j];
  }
  float r = sbc3[0];
#pragma unroll
  for (int k = 0; k < 32; k++) {
    float c = c2[k] > 0.0f ? c2[k] : 0.0f;
    r += c * sWc3[k];
  }
  out[node] = r;
}

// ---------------------------------------------------------------------------
extern "C" void kernel_launch(void* const* d_in, const int* in_sizes, int n_in,
                              void* d_out, int out_size, void* d_ws, size_t ws_size,
                              hipStream_t stream) {
  const float* x   = (const float*)d_in[0];
  const int* ei    = (const int*)d_in[1];
  const float* Wi  = (const float*)d_in[2];
  const float* bi  = (const float*)d_in[3];
  const float* g1  = (const float*)d_in[4];
  const float* b1  = (const float*)d_in[5];
  const float* Wg1 = (const float*)d_in[6];
  const float* bg1 = (const float*)d_in[7];
  const float* Wg2 = (const float*)d_in[8];
  const float* bg2 = (const float*)d_in[9];
  const float* g2  = (const float*)d_in[10];
  const float* b2  = (const float*)d_in[11];
  const float* Wg3 = (const float*)d_in[12];
  const float* bg3 = (const float*)d_in[13];
  // d_in[14..17]: Wq,bq,Wk,bk — mathematically dead (softmax over 1 key == 1)
  const float* Wv  = (const float*)d_in[18];
  const float* bv  = (const float*)d_in[19];
  const float* Wo  = (const float*)d_in[20];
  const float* bo  = (const float*)d_in[21];
  const float* Wc1 = (const float*)d_in[22];
  const float* bc1 = (const float*)d_in[23];
  const float* Wc2 = (const float*)d_in[24];
  const float* bc2 = (const float*)d_in[25];
  const float* Wc3 = (const float*)d_in[26];
  const float* bc3 = (const float*)d_in[27];

  const int n = in_sizes[0] / 164;
  const int e = in_sizes[1] / 2;
  const int* src = ei;
  const int* dst = ei + e;

  // workspace layout (256B aligned)
  char* ws = (char*)d_ws;
  size_t off = 0;
  auto alloc = [&](size_t bytes) {
    char* p = ws + off;
    off += (bytes + 255) & ~(size_t)255;
    return p;
  };
  _Float16* A     = (_Float16*)alloc((size_t)n * 128 * 2);
  _Float16* B     = (_Float16*)alloc((size_t)n * 128 * 2);
  _Float16* C     = (_Float16*)alloc((size_t)n * 128 * 2);
  float* dinv     = (float*)alloc((size_t)n * 4);
  int*   counts   = (int*)alloc((size_t)n * 4);      // reused as fill cursor
  int*   offsets  = (int*)alloc((size_t)(n + 1) * 4);
  int*   bsums    = (int*)alloc(128 * 4);
  int2*  csr      = (int2*)alloc((size_t)e * 8);
  _Float16* pWi   = (_Float16*)alloc(6 * 8 * 512 * 2);       // 48 KB, hi only
  _Float16* pWg1  = (_Float16*)alloc(4 * 8 * 1024 * 2);      // 64 KB hi/lo
  _Float16* pWg2  = (_Float16*)alloc(4 * 4 * 1024 * 2);      // 32 KB
  _Float16* pWg3  = (_Float16*)alloc(2 * 2 * 1024 * 2);      // 8 KB
  (void)ws_size;

  const int BS = 256;
  const int SB = (n + 1023) / 1024;  // scan blocks (98 for n=100k, <=128)
  const int GB = (n + 127) / 128;    // gemm blocks (512 thr, 128 rows)

  // ---- setup: weight prepack + zero counts (one kernel) ----
  k_setup<<<25 + (n + 255) / 256, 256, 0, stream>>>(
      Wi, Wg1, Wg2, Wg3, pWi, pWg1, pWg2, pWg3, counts, n);

  // ---- CSR build (shared by all three convs) ----
  k_count<<<(e + BS - 1) / BS, BS, 0, stream>>>(dst, counts, e);
  k_scan_part<<<SB, 256, 0, stream>>>(counts, bsums, n);
  k_scan_top<<<1, 128, 0, stream>>>(bsums, SB);
  k_scan_down<<<SB, 256, 0, stream>>>(counts, bsums, offsets, dinv, n, e);
  k_fill<<<(e + BS - 1) / BS, BS, 0, stream>>>(src, dst, offsets, counts, dinv,
                                               csr, e);

  // ---- input layer: A = h = LN(relu(x@Wi+bi))  [fp16] ----
  k_gemm_in<<<GB, 512, 0, stream>>>(x, pWi, bi, g1, b1, A, n);

  // ---- conv1: B = xw1 = h@Wg1; gather -> C = h1 = relu(agg)+h ----
  k_gemm_f16<128, 128><<<GB, 512, 0, stream>>>(A, pWg1, B, n);
  k_gather<128, 0><<<(n + 7) / 8, 256, 0, stream>>>(
      offsets, csr, B, dinv, bg1, A, nullptr, nullptr, C, n);

  // ---- conv2: A = xw2 = h1@Wg2 [n,64]; gather -> B = h2 = LN(relu(agg)) ----
  k_gemm_f16<128, 64><<<GB, 512, 0, stream>>>(C, pWg2, A, n);
  k_gather<64, 1><<<(n + 15) / 16, 256, 0, stream>>>(
      offsets, csr, A, dinv, bg2, nullptr, g2, b2, B, n);

  // ---- conv3: A = xw3 = h2@Wg3 [n,32]; gather -> C = agg3 [fp16] ----
  k_gemm_f16<64, 32><<<GB, 512, 0, stream>>>(B, pWg3, A, n);
  k_gather<32, 2><<<(n + 31) / 32, 256, 0, stream>>>(
      offsets, csr, A, dinv, bg3, nullptr, nullptr, nullptr, C, n);

  // ---- tail: relu(agg3) -> MHA(v,o) -> MLP -> out ----
  k_tail<<<(n + BS - 1) / BS, BS, 0, stream>>>(
      C, Wv, bv, Wo, bo, Wc1, bc1, Wc2, bc2, Wc3, bc3, (float*)d_out, n);
}

// Round 8
// 226.050 us; speedup vs baseline: 5.3172x; 1.0056x over previous
//
#include <hip/hip_runtime.h>

// ---------------------------------------------------------------------------
// EnhancedBitcoinGCN: 3x GCNConv + LN/residual + (trivial) MHA + MLP head
// N=100000 nodes, E=600000 edges, dims 164->128->128->64->32->16->32->1
// Round 7 -> 8 (register-budget round):
//  * Round 7's load hoists never materialized: k_gemm_in VGPR=48 (11 float4
//    need 44) and k_gather VGPR=12 (8-deep f16x4 batch needs >16) -> the
//    compiler's default occupancy target serialized the loads.
//  * __launch_bounds__(512, 4) on GEMMs (VGPR cap 128, 2 blocks/CU) and
//    __launch_bounds__(256, 2) on gathers (cap 256) so hoisted loads stay
//    in flight. Gather batch rewritten as named scalars; self/residual row
//    loads hoisted above the edge loop.
// ---------------------------------------------------------------------------

typedef __attribute__((ext_vector_type(8))) _Float16 f16x8;
typedef __attribute__((ext_vector_type(4))) _Float16 f16x4;
typedef __attribute__((ext_vector_type(4))) float f32x4;

// ---------------- CSR build ----------------
__global__ void k_count(const int* __restrict__ dst, int* __restrict__ counts, int e) {
  int i = blockIdx.x * blockDim.x + threadIdx.x;
  if (i < e) atomicAdd(&counts[dst[i]], 1);
}

__global__ __launch_bounds__(256) void k_scan_part(
    const int* __restrict__ counts, int* __restrict__ bsums, int n) {
  int tid = threadIdx.x;
  int i0 = blockIdx.x * 1024 + tid * 4;
  int s = 0;
#pragma unroll
  for (int k = 0; k < 4; k++) { int i = i0 + k; if (i < n) s += counts[i]; }
#pragma unroll
  for (int d = 1; d < 64; d <<= 1) s += __shfl_xor(s, d);
  __shared__ int wsum[4];
  int lane = tid & 63, w = tid >> 6;
  if (lane == 0) wsum[w] = s;
  __syncthreads();
  if (tid == 0) bsums[blockIdx.x] = wsum[0] + wsum[1] + wsum[2] + wsum[3];
}

__global__ __launch_bounds__(128) void k_scan_top(int* __restrict__ bsums, int nb) {
  int tid = threadIdx.x;
  int orig = (tid < nb) ? bsums[tid] : 0;
  int v = orig;
  int lane = tid & 63, w = tid >> 6;
#pragma unroll
  for (int d = 1; d < 64; d <<= 1) { int t = __shfl_up(v, d); if (lane >= d) v += t; }
  __shared__ int ws[2];
  if (lane == 63) ws[w] = v;
  __syncthreads();
  if (w == 1) v += ws[0];
  if (tid < nb) bsums[tid] = v - orig;  // exclusive
}

// offsets + dinv + (counts -> 0, becoming the fill cursor)
__global__ __launch_bounds__(256) void k_scan_down(
    int* __restrict__ counts, const int* __restrict__ bsums,
    int* __restrict__ offsets, float* __restrict__ dinv, int n, int e) {
  int tid = threadIdx.x;
  int i0 = blockIdx.x * 1024 + tid * 4;
  int c[4]; int tsum = 0;
#pragma unroll
  for (int k = 0; k < 4; k++) { int i = i0 + k; c[k] = (i < n) ? counts[i] : 0; tsum += c[k]; }
  int v = tsum;
  int lane = tid & 63, w = tid >> 6;
#pragma unroll
  for (int d = 1; d < 64; d <<= 1) { int t = __shfl_up(v, d); if (lane >= d) v += t; }
  __shared__ int wsum[4];
  if (lane == 63) wsum[w] = v;
  __syncthreads();
  int wadd = 0;
#pragma unroll
  for (int q = 0; q < 4; q++) if (q < w) wadd += wsum[q];
  int run = (v - tsum) + wadd + bsums[blockIdx.x];
#pragma unroll
  for (int k = 0; k < 4; k++) {
    int i = i0 + k;
    if (i < n) {
      offsets[i] = run;
      dinv[i] = rsqrtf((float)(c[k] + 1));
      counts[i] = 0;  // becomes fill cursor
    }
    run += c[k];
  }
  if (blockIdx.x == 0 && tid == 0) offsets[n] = e;
}

// packed edge record: {src, norm as bits} -> one 8B meta load in gather
__global__ void k_fill(const int* __restrict__ src, const int* __restrict__ dst,
                       const int* __restrict__ offsets, int* __restrict__ cursor,
                       const float* __restrict__ dinv, int2* __restrict__ csr, int e) {
  int i = blockIdx.x * blockDim.x + threadIdx.x;
  if (i >= e) return;
  int s = src[i], d = dst[i];
  int pos = atomicAdd(&cursor[d], 1);
  csr[offsets[d] + pos] = make_int2(s, __float_as_int(dinv[s] * dinv[d]));
}

// ---------------- weight prepack (fragment-ordered fp16 hi/lo) -------------
// B fragment for mfma_f32_16x16x32_f16: lane l holds B[ks*32+(l>>4)*8+i][ct*16+(l&15)]
__device__ __forceinline__ void pack_hi(const float* __restrict__ W,
                                        _Float16* __restrict__ dst,
                                        int K, int N, int u) {
  int lane = u & 63; int rest = u >> 6; int CT = N >> 4;
  int ct = rest % CT, ks = rest / CT;
  int gcol = ct * 16 + (lane & 15);
  int gk0 = ks * 32 + (lane >> 4) * 8;
  size_t o = (size_t)(ks * CT + ct) * 512 + lane * 8;
#pragma unroll
  for (int i = 0; i < 8; i++) {
    float v = (gk0 + i < K) ? W[(size_t)(gk0 + i) * N + gcol] : 0.0f;
    dst[o + i] = (_Float16)v;
  }
}

__device__ __forceinline__ void pack_hl(const float* __restrict__ W,
                                        _Float16* __restrict__ dst,
                                        int K, int N, int u) {
  int lane = u & 63; int rest = u >> 6; int CT = N >> 4;
  int ct = rest % CT, ks = rest / CT;
  int gcol = ct * 16 + (lane & 15);
  int gk0 = ks * 32 + (lane >> 4) * 8;
  size_t oh = (size_t)((ks * CT + ct) * 2) * 512 + lane * 8;
#pragma unroll
  for (int i = 0; i < 8; i++) {
    float v = (gk0 + i < K) ? W[(size_t)(gk0 + i) * N + gcol] : 0.0f;
    _Float16 h = (_Float16)v;
    dst[oh + i] = h;
    dst[oh + 512 + i] = (_Float16)(v - (float)h);
  }
}

// blocks [0,25): prepack (6400 units); blocks [25,..): zero counts
__global__ void k_setup(const float* __restrict__ Wi, const float* __restrict__ Wg1,
                        const float* __restrict__ Wg2, const float* __restrict__ Wg3,
                        _Float16* __restrict__ pWi, _Float16* __restrict__ pWg1,
                        _Float16* __restrict__ pWg2, _Float16* __restrict__ pWg3,
                        int* __restrict__ counts, int n) {
  int b = blockIdx.x;
  if (b < 25) {
    int t = b * 256 + threadIdx.x;
    if (t < 3072) pack_hi(Wi, pWi, 164, 128, t);
    else if (t < 5120) pack_hl(Wg1, pWg1, 128, 128, t - 3072);
    else if (t < 6144) pack_hl(Wg2, pWg2, 128, 64, t - 5120);
    else if (t < 6400) pack_hl(Wg3, pWg3, 64, 32, t - 6144);
  } else {
    int i = (b - 25) * 256 + threadIdx.x;
    if (i < n) counts[i] = 0;
  }
}

// ---------------- input GEMM: h = LN(relu(x@Wi+bi)) ----------------
// 512 thr / 8 waves, 128 rows/block. All 11 float4 x-loads in flight
// (launch_bounds(512,4): VGPR cap 128 so the hoist actually holds).
__global__ __launch_bounds__(512, 4) void k_gemm_in(
    const float* __restrict__ x, const _Float16* __restrict__ pB,
    const float* __restrict__ bias, const float* __restrict__ gamma,
    const float* __restrict__ beta, _Float16* __restrict__ out, int n) {
  constexpr int K = 164, N = 128, CT = 8;
  __shared__ __align__(16) _Float16 sB[6 * CT * 512];  // 48 KB
  int tid = threadIdx.x;
  {
    const f16x8* s = (const f16x8*)pB;
    f16x8* d = (f16x8*)sB;
    for (int i = tid; i < 6 * CT * 64; i += 512) d[i] = s[i];
  }
  __syncthreads();
  int lane = tid & 63, w = tid >> 6;
  int row = blockIdx.x * 128 + w * 16 + (lane & 15);
  bool rv = row < n;
  int kof = (lane >> 4) * 8;
  // hoist all x loads: ks 0..4 full (2 float4 each), ks 5 only kof==0 (k=160..163)
  float4 xv[11];
#pragma unroll
  for (int i = 0; i < 11; i++) xv[i] = make_float4(0.f, 0.f, 0.f, 0.f);
  if (rv) {
    const float4* p = (const float4*)(x + (size_t)row * K + kof);
#pragma unroll
    for (int ks = 0; ks < 5; ks++) { xv[2 * ks] = p[ks * 8]; xv[2 * ks + 1] = p[ks * 8 + 1]; }
    if (kof == 0) xv[10] = *(const float4*)(x + (size_t)row * K + 160);
  }
  f32x4 acc[CT];
#pragma unroll
  for (int c = 0; c < CT; c++) acc[c] = (f32x4)0.0f;
#pragma unroll
  for (int ks = 0; ks < 6; ks++) {
    float v[8];
    if (ks < 5) {
      float4 u0 = xv[2 * ks], u1 = xv[2 * ks + 1];
      v[0] = u0.x; v[1] = u0.y; v[2] = u0.z; v[3] = u0.w;
      v[4] = u1.x; v[5] = u1.y; v[6] = u1.z; v[7] = u1.w;
    } else {
      float4 u0 = xv[10];
      v[0] = u0.x; v[1] = u0.y; v[2] = u0.z; v[3] = u0.w;
      v[4] = 0.f; v[5] = 0.f; v[6] = 0.f; v[7] = 0.f;
    }
    f16x8 ah, al;
#pragma unroll
    for (int i = 0; i < 8; i++) {
      ah[i] = (_Float16)v[i];
      al[i] = (_Float16)(v[i] - (float)ah[i]);
    }
#pragma unroll
    for (int c = 0; c < CT; c++) {
      f16x8 b = ((const f16x8*)sB)[(ks * CT + c) * 64 + lane];
      acc[c] = __builtin_amdgcn_mfma_f32_16x16x32_f16(ah, b, acc[c], 0, 0, 0);
      acc[c] = __builtin_amdgcn_mfma_f32_16x16x32_f16(al, b, acc[c], 0, 0, 0);
    }
  }
  // bias + relu + LN over N cols (row lives in a 16-lane group)
  int r0 = (lane >> 4) * 4;
  int li = lane & 15;
  float s1[4] = {0, 0, 0, 0}, s2[4] = {0, 0, 0, 0};
#pragma unroll
  for (int c = 0; c < CT; c++) {
    float bb = bias[c * 16 + li];
#pragma unroll
    for (int r = 0; r < 4; r++) {
      float t = acc[c][r] + bb;
      t = t > 0.0f ? t : 0.0f;
      acc[c][r] = t;
      s1[r] += t;
      s2[r] += t * t;
    }
  }
#pragma unroll
  for (int m = 1; m < 16; m <<= 1) {
#pragma unroll
    for (int r = 0; r < 4; r++) {
      s1[r] += __shfl_xor(s1[r], m);
      s2[r] += __shfl_xor(s2[r], m);
    }
  }
#pragma unroll
  for (int c = 0; c < CT; c++) {
    float gv = gamma[c * 16 + li], bv = beta[c * 16 + li];
#pragma unroll
    for (int r = 0; r < 4; r++) {
      int node = blockIdx.x * 128 + w * 16 + r0 + r;
      if (node < n) {
        float mean = s1[r] * (1.0f / N);
        float var = s2[r] * (1.0f / N) - mean * mean;
        float rs = rsqrtf(var + 1e-5f);
        out[(size_t)node * N + c * 16 + li] =
            (_Float16)((acc[c][r] - mean) * rs * gv + bv);
      }
    }
  }
}

// ---------------- conv GEMM: xw = A@W (A exact fp16, W hi/lo fp16) ----------
template <int K, int N>
__global__ __launch_bounds__(512, 4) void k_gemm_f16(
    const _Float16* __restrict__ A, const _Float16* __restrict__ pB,
    _Float16* __restrict__ out, int n) {
  constexpr int KS = K / 32, CT = N / 16;
  __shared__ __align__(16) _Float16 sB[KS * CT * 1024];  // <=64 KB (conv1)
  int tid = threadIdx.x;
  {
    const f16x8* s = (const f16x8*)pB;
    f16x8* d = (f16x8*)sB;
    for (int i = tid; i < KS * CT * 128; i += 512) d[i] = s[i];
  }
  __syncthreads();
  int lane = tid & 63, w = tid >> 6;
  int row = blockIdx.x * 128 + w * 16 + (lane & 15);
  bool rv = row < n;
  const _Float16* ar = A + (size_t)row * K + (lane >> 4) * 8;
  // hoist all A-fragment loads
  f16x8 av[KS];
#pragma unroll
  for (int ks = 0; ks < KS; ks++) {
    if (rv) av[ks] = *(const f16x8*)(ar + ks * 32);
    else {
#pragma unroll
      for (int i = 0; i < 8; i++) av[ks][i] = (_Float16)0.0f;
    }
  }
  f32x4 acc[CT];
#pragma unroll
  for (int c = 0; c < CT; c++) acc[c] = (f32x4)0.0f;
#pragma unroll
  for (int ks = 0; ks < KS; ks++) {
#pragma unroll
    for (int c = 0; c < CT; c++) {
      f16x8 bh = ((const f16x8*)sB)[((ks * CT + c) * 2) * 64 + lane];
      f16x8 bl = ((const f16x8*)sB)[((ks * CT + c) * 2 + 1) * 64 + lane];
      acc[c] = __builtin_amdgcn_mfma_f32_16x16x32_f16(av[ks], bh, acc[c], 0, 0, 0);
      acc[c] = __builtin_amdgcn_mfma_f32_16x16x32_f16(av[ks], bl, acc[c], 0, 0, 0);
    }
  }
  int r0 = (lane >> 4) * 4;
  int li = lane & 15;
#pragma unroll
  for (int c = 0; c < CT; c++) {
#pragma unroll
    for (int r = 0; r < 4; r++) {
      int node = blockIdx.x * 128 + w * 16 + r0 + r;
      if (node < n) out[(size_t)node * N + c * 16 + li] = (_Float16)acc[c][r];
    }
  }
}

// ---------------- dst-side gather, 4 cols/thread, 8-deep load batches ------
// launch_bounds(256,2) raises the VGPR cap so the 8 loads are truly in
// flight. Idle meta lanes padded with {node, w=0} (self row is L1-hot).
// MODE 0: out = relu(agg) + auxh[node]      (conv1)
// MODE 1: out = LN(relu(agg); gamma, beta)  (conv2)
// MODE 2: out = agg                         (conv3; tail applies relu)
template <int OUT_D, int MODE>
__global__ __launch_bounds__(256, 2) void k_gather(
    const int* __restrict__ off, const int2* __restrict__ csr,
    const _Float16* __restrict__ xw, const float* __restrict__ dinv,
    const float* __restrict__ bias, const _Float16* __restrict__ auxh,
    const float* __restrict__ gamma, const float* __restrict__ beta,
    _Float16* __restrict__ out, int n) {
  constexpr int TPN = OUT_D / 4;   // threads per node (32/16/8)
  constexpr int NPB = 256 / TPN;
  int tid = threadIdx.x;
  int node = blockIdx.x * NPB + tid / TPN;
  int li = tid % TPN;
  if (node >= n) return;
  int start = off[node], end = off[node + 1];
  float di = dinv[node];
  float d2 = di * di;
  const _Float16* xp = xw + 4 * li;
  // hoist self row + residual row above the edge loop (latency overlap)
  f16x4 self = *(const f16x4*)(xp + (size_t)node * OUT_D);
  f16x4 hres;
  if constexpr (MODE == 0)
    hres = *(const f16x4*)(auxh + (size_t)node * OUT_D + 4 * li);
  float a0 = (float)self[0] * d2 + bias[4 * li + 0];
  float a1 = (float)self[1] * d2 + bias[4 * li + 1];
  float a2 = (float)self[2] * d2 + bias[4 * li + 2];
  float a3 = (float)self[3] * d2 + bias[4 * li + 3];
  for (int cb = start; cb < end; cb += TPN) {
    int m = end - cb; if (m > TPN) m = TPN;
    int sv = node; float nv = 0.0f;                 // pad: self row, weight 0
    if (li < m) { int2 me = csr[cb + li]; sv = me.x; nv = __int_as_float(me.y); }
    for (int j0 = 0; j0 < m; j0 += 8) {
      int s0 = __shfl(sv, j0 + 0, TPN), s1 = __shfl(sv, j0 + 1, TPN);
      int s2 = __shfl(sv, j0 + 2, TPN), s3 = __shfl(sv, j0 + 3, TPN);
      int s4 = __shfl(sv, j0 + 4, TPN), s5 = __shfl(sv, j0 + 5, TPN);
      int s6 = __shfl(sv, j0 + 6, TPN), s7 = __shfl(sv, j0 + 7, TPN);
      float w0 = __shfl(nv, j0 + 0, TPN), w1 = __shfl(nv, j0 + 1, TPN);
      float w2 = __shfl(nv, j0 + 2, TPN), w3 = __shfl(nv, j0 + 3, TPN);
      float w4 = __shfl(nv, j0 + 4, TPN), w5 = __shfl(nv, j0 + 5, TPN);
      float w6 = __shfl(nv, j0 + 6, TPN), w7 = __shfl(nv, j0 + 7, TPN);
      f16x4 v0 = *(const f16x4*)(xp + (size_t)s0 * OUT_D);
      f16x4 v1 = *(const f16x4*)(xp + (size_t)s1 * OUT_D);
      f16x4 v2 = *(const f16x4*)(xp + (size_t)s2 * OUT_D);
      f16x4 v3 = *(const f16x4*)(xp + (size_t)s3 * OUT_D);
      f16x4 v4 = *(const f16x4*)(xp + (size_t)s4 * OUT_D);
      f16x4 v5 = *(const f16x4*)(xp + (size_t)s5 * OUT_D);
      f16x4 v6 = *(const f16x4*)(xp + (size_t)s6 * OUT_D);
      f16x4 v7 = *(const f16x4*)(xp + (size_t)s7 * OUT_D);
      a0 += (float)v0[0] * w0 + (float)v1[0] * w1 + (float)v2[0] * w2 + (float)v3[0] * w3
          + (float)v4[0] * w4 + (float)v5[0] * w5 + (float)v6[0] * w6 + (float)v7[0] * w7;
      a1 += (float)v0[1] * w0 + (float)v1[1] * w1 + (float)v2[1] * w2 + (float)v3[1] * w3
          + (float)v4[1] * w4 + (float)v5[1] * w5 + (float)v6[1] * w6 + (float)v7[1] * w7;
      a2 += (float)v0[2] * w0 + (float)v1[2] * w1 + (float)v2[2] * w2 + (float)v3[2] * w3
          + (float)v4[2] * w4 + (float)v5[2] * w5 + (float)v6[2] * w6 + (float)v7[2] * w7;
      a3 += (float)v0[3] * w0 + (float)v1[3] * w1 + (float)v2[3] * w2 + (float)v3[3] * w3
          + (float)v4[3] * w4 + (float)v5[3] * w5 + (float)v6[3] * w6 + (float)v7[3] * w7;
    }
  }
  _Float16* po = out + (size_t)node * OUT_D + 4 * li;
  if constexpr (MODE == 0) {
    f16x4 o;
    o[0] = (_Float16)((a0 > 0.0f ? a0 : 0.0f) + (float)hres[0]);
    o[1] = (_Float16)((a1 > 0.0f ? a1 : 0.0f) + (float)hres[1]);
    o[2] = (_Float16)((a2 > 0.0f ? a2 : 0.0f) + (float)hres[2]);
    o[3] = (_Float16)((a3 > 0.0f ? a3 : 0.0f) + (float)hres[3]);
    *(f16x4*)po = o;
  } else if constexpr (MODE == 1) {
    float v0 = a0 > 0.0f ? a0 : 0.0f, v1 = a1 > 0.0f ? a1 : 0.0f;
    float v2 = a2 > 0.0f ? a2 : 0.0f, v3 = a3 > 0.0f ? a3 : 0.0f;
    float s1 = v0 + v1 + v2 + v3;
    float s2 = v0 * v0 + v1 * v1 + v2 * v2 + v3 * v3;
#pragma unroll
    for (int d = 1; d < TPN; d <<= 1) {
      s1 += __shfl_xor(s1, d, TPN);
      s2 += __shfl_xor(s2, d, TPN);
    }
    float m_ = s1 * (1.0f / OUT_D);
    float var = s2 * (1.0f / OUT_D) - m_ * m_;
    float rs = rsqrtf(var + 1e-5f);
    f16x4 o;
    o[0] = (_Float16)((v0 - m_) * rs * gamma[4 * li + 0] + beta[4 * li + 0]);
    o[1] = (_Float16)((v1 - m_) * rs * gamma[4 * li + 1] + beta[4 * li + 1]);
    o[2] = (_Float16)((v2 - m_) * rs * gamma[4 * li + 2] + beta[4 * li + 2]);
    o[3] = (_Float16)((v3 - m_) * rs * gamma[4 * li + 3] + beta[4 * li + 3]);
    *(f16x4*)po = o;
  } else {
    f16x4 o;
    o[0] = (_Float16)a0; o[1] = (_Float16)a1;
    o[2] = (_Float16)a2; o[3] = (_Float16)a3;
    *(f16x4*)po = o;
  }
}

// ---------------- tail: relu(agg3) -> Wv -> Wo -> Wc1 -> Wc2 -> Wc3 --------
// (MHA with seq_len==1: softmax over one key == 1, so out = (x@Wv+bv)@Wo+bo)
__global__ __launch_bounds__(256) void k_tail(
    const _Float16* __restrict__ agg3, const float* __restrict__ Wv,
    const float* __restrict__ bv, const float* __restrict__ Wo,
    const float* __restrict__ bo, const float* __restrict__ Wc1,
    const float* __restrict__ bc1, const float* __restrict__ Wc2,
    const float* __restrict__ bc2, const float* __restrict__ Wc3,
    const float* __restrict__ bc3, float* __restrict__ out, int n) {
  __shared__ float sWv[1024], sWo[1024], sWc1[512], sWc2[512];
  __shared__ float sbv[32], sbo[32], sbc2[32], sWc3[32], sbc1[16], sbc3[1];
  int tid = threadIdx.x;
  for (int i = tid; i < 1024; i += 256) { sWv[i] = Wv[i]; sWo[i] = Wo[i]; }
  for (int i = tid; i < 512; i += 256) { sWc1[i] = Wc1[i]; sWc2[i] = Wc2[i]; }
  if (tid < 32) { sbv[tid] = bv[tid]; sbo[tid] = bo[tid];
                  sbc2[tid] = bc2[tid]; sWc3[tid] = Wc3[tid]; }
  if (tid < 16) sbc1[tid] = bc1[tid];
  if (tid == 0) sbc3[0] = bc3[0];
  __syncthreads();
  int node = blockIdx.x * blockDim.x + tid;
  if (node >= n) return;
  float a[32];
  const f16x8* row8 = (const f16x8*)(agg3 + (size_t)node * 32);
#pragma unroll
  for (int q = 0; q < 4; q++) {
    f16x8 t = row8[q];
#pragma unroll
    for (int i = 0; i < 8; i++) {
      float f = (float)t[i];
      a[8 * q + i] = f > 0.0f ? f : 0.0f;
    }
  }
  float v[32];
#pragma unroll
  for (int j = 0; j < 32; j++) v[j] = sbv[j];
  for (int k = 0; k < 32; k++) {
#pragma unroll
    for (int j = 0; j < 32; j++) v[j] += a[k] * sWv[k * 32 + j];
  }
  float o[32];
#pragma unroll
  for (int j = 0; j < 32; j++) o[j] = sbo[j];
  for (int k = 0; k < 32; k++) {
#pragma unroll
    for (int j = 0; j < 32; j++) o[j] += v[k] * sWo[k * 32 + j];
  }
  float c1[16];
#pragma unroll
  for (int j = 0; j < 16; j++) c1[j] = sbc1[j];
  for (int k = 0; k < 32; k++) {
#pragma unroll
    for (int j = 0; j < 16; j++) c1[j] += o[k] * sWc1[k * 16 + j];
  }
#pragma unroll
  for (int j = 0; j < 16; j++) c1[j] = c1[j] > 0.0f ? c1[j] : 0.0f;
  float c2[32];
#pragma unroll
  for (int j = 0; j < 32; j++) c2[j] = sbc2[j];
  for (int k = 0; k < 16; k++) {
#pragma unroll
    for (int j = 0; j < 32; j++) c2[j] += c1[k] * sWc2[k * 32 + j];
  }
  float r = sbc3[0];
#pragma unroll
  for (int k = 0; k < 32; k++) {
    float c = c2[k] > 0.0f ? c2[k] : 0.0f;
    r += c * sWc3[k];
  }
  out[node] = r;
}

// ---------------------------------------------------------------------------
extern "C" void kernel_launch(void* const* d_in, const int* in_sizes, int n_in,
                              void* d_out, int out_size, void* d_ws, size_t ws_size,
                              hipStream_t stream) {
  const float* x   = (const float*)d_in[0];
  const int* ei    = (const int*)d_in[1];
  const float* Wi  = (const float*)d_in[2];
  const float* bi  = (const float*)d_in[3];
  const float* g1  = (const float*)d_in[4];
  const float* b1  = (const float*)d_in[5];
  const float* Wg1 = (const float*)d_in[6];
  const float* bg1 = (const float*)d_in[7];
  const float* Wg2 = (const float*)d_in[8];
  const float* bg2 = (const float*)d_in[9];
  const float* g2  = (const float*)d_in[10];
  const float* b2  = (const float*)d_in[11];
  const float* Wg3 = (const float*)d_in[12];
  const float* bg3 = (const float*)d_in[13];
  // d_in[14..17]: Wq,bq,Wk,bk — mathematically dead (softmax over 1 key == 1)
  const float* Wv  = (const float*)d_in[18];
  const float* bv  = (const float*)d_in[19];
  const float* Wo  = (const float*)d_in[20];
  const float* bo  = (const float*)d_in[21];
  const float* Wc1 = (const float*)d_in[22];
  const float* bc1 = (const float*)d_in[23];
  const float* Wc2 = (const float*)d_in[24];
  const float* bc2 = (const float*)d_in[25];
  const float* Wc3 = (const float*)d_in[26];
  const float* bc3 = (const float*)d_in[27];

  const int n = in_sizes[0] / 164;
  const int e = in_sizes[1] / 2;
  const int* src = ei;
  const int* dst = ei + e;

  // workspace layout (256B aligned)
  char* ws = (char*)d_ws;
  size_t off = 0;
  auto alloc = [&](size_t bytes) {
    char* p = ws + off;
    off += (bytes + 255) & ~(size_t)255;
    return p;
  };
  _Float16* A     = (_Float16*)alloc((size_t)n * 128 * 2);
  _Float16* B     = (_Float16*)alloc((size_t)n * 128 * 2);
  _Float16* C     = (_Float16*)alloc((size_t)n * 128 * 2);
  float* dinv     = (float*)alloc((size_t)n * 4);
  int*   counts   = (int*)alloc((size_t)n * 4);      // reused as fill cursor
  int*   offsets  = (int*)alloc((size_t)(n + 1) * 4);
  int*   bsums    = (int*)alloc(128 * 4);
  int2*  csr      = (int2*)alloc((size_t)e * 8);
  _Float16* pWi   = (_Float16*)alloc(6 * 8 * 512 * 2);       // 48 KB, hi only
  _Float16* pWg1  = (_Float16*)alloc(4 * 8 * 1024 * 2);      // 64 KB hi/lo
  _Float16* pWg2  = (_Float16*)alloc(4 * 4 * 1024 * 2);      // 32 KB
  _Float16* pWg3  = (_Float16*)alloc(2 * 2 * 1024 * 2);      // 8 KB
  (void)ws_size;

  const int BS = 256;
  const int SB = (n + 1023) / 1024;  // scan blocks (98 for n=100k, <=128)
  const int GB = (n + 127) / 128;    // gemm blocks (512 thr, 128 rows)

  // ---- setup: weight prepack + zero counts (one kernel) ----
  k_setup<<<25 + (n + 255) / 256, 256, 0, stream>>>(
      Wi, Wg1, Wg2, Wg3, pWi, pWg1, pWg2, pWg3, counts, n);

  // ---- CSR build (shared by all three convs) ----
  k_count<<<(e + BS - 1) / BS, BS, 0, stream>>>(dst, counts, e);
  k_scan_part<<<SB, 256, 0, stream>>>(counts, bsums, n);
  k_scan_top<<<1, 128, 0, stream>>>(bsums, SB);
  k_scan_down<<<SB, 256, 0, stream>>>(counts, bsums, offsets, dinv, n, e);
  k_fill<<<(e + BS - 1) / BS, BS, 0, stream>>>(src, dst, offsets, counts, dinv,
                                               csr, e);

  // ---- input layer: A = h = LN(relu(x@Wi+bi))  [fp16] ----
  k_gemm_in<<<GB, 512, 0, stream>>>(x, pWi, bi, g1, b1, A, n);

  // ---- conv1: B = xw1 = h@Wg1; gather -> C = h1 = relu(agg)+h ----
  k_gemm_f16<128, 128><<<GB, 512, 0, stream>>>(A, pWg1, B, n);
  k_gather<128, 0><<<(n + 7) / 8, 256, 0, stream>>>(
      offsets, csr, B, dinv, bg1, A, nullptr, nullptr, C, n);

  // ---- conv2: A = xw2 = h1@Wg2 [n,64]; gather -> B = h2 = LN(relu(agg)) ----
  k_gemm_f16<128, 64><<<GB, 512, 0, stream>>>(C, pWg2, A, n);
  k_gather<64, 1><<<(n + 15) / 16, 256, 0, stream>>>(
      offsets, csr, A, dinv, bg2, nullptr, g2, b2, B, n);

  // ---- conv3: A = xw3 = h2@Wg3 [n,32]; gather -> C = agg3 [fp16] ----
  k_gemm_f16<64, 32><<<GB, 512, 0, stream>>>(B, pWg3, A, n);
  k_gather<32, 2><<<(n + 31) / 32, 256, 0, stream>>>(
      offsets, csr, A, dinv, bg3, nullptr, nullptr, nullptr, C, n);

  // ---- tail: relu(agg3) -> MHA(v,o) -> MLP -> out ----
  k_tail<<<(n + BS - 1) / BS, BS, 0, stream>>>(
      C, Wv, bv, Wo, bo, Wc1, bc1, Wc2, bc2, Wc3, bc3, (float*)d_out, n);
}